// Round 1
// baseline (7209.029 us; speedup 1.0000x reference)
//
#include <hip/hip_runtime.h>
#include <math.h>

#define NN0 20000
#define NN1 60000
#define NN2 40000
#define CC 256
#define OUTD 64
#define BB 8

// ---------------------------------------------------------------------------
// zero kernel (grid-stride, float4)
// ---------------------------------------------------------------------------
__global__ void zero_kernel(float4* __restrict__ p, long n4) {
    long i = (long)blockIdx.x * blockDim.x + threadIdx.x;
    long stride = (long)gridDim.x * blockDim.x;
    for (; i < n4; i += stride) p[i] = make_float4(0.f, 0.f, 0.f, 0.f);
}

// ---------------------------------------------------------------------------
// T = X (N x 256) @ W (256 x 256), fp32, 64x64 tile, 4x4 microtile
// grid: (ceil(N/64), 4), block: 256
// ---------------------------------------------------------------------------
__global__ __launch_bounds__(256) void gemm_nx256(const float* __restrict__ X,
                                                  const float* __restrict__ W,
                                                  float* __restrict__ T, int N) {
    __shared__ float As[16][68];   // k-major (transposed), stride 68 keeps conflicts <=2-way
    __shared__ float Bs[16][64];
    const int t    = threadIdx.x;
    const int row0 = blockIdx.x * 64;
    const int col0 = blockIdx.y * 64;
    const int tx = t & 15, ty = t >> 4;
    const int m0 = ty * 4, n0 = tx * 4;
    // A-load mapping: 64 rows x 4 float4 k-chunks
    const int lr = t >> 2;          // 0..63 row in tile
    const int lk = (t & 3) * 4;     // 0,4,8,12 k offset
    // B-load mapping: 16 k-rows x 16 float4 col-chunks
    const int wk = t >> 4;          // 0..15
    const int wc = (t & 15) * 4;    // 0..60

    int ar = row0 + lr; if (ar > N - 1) ar = N - 1;   // clamp (stores guarded)
    const float* aptr = X + (size_t)ar * CC;

    float acc[4][4] = {};

    for (int kk = 0; kk < CC; kk += 16) {
        float4 av = *(const float4*)(aptr + kk + lk);
        As[lk + 0][lr] = av.x;
        As[lk + 1][lr] = av.y;
        As[lk + 2][lr] = av.z;
        As[lk + 3][lr] = av.w;
        *(float4*)&Bs[wk][wc] = *(const float4*)&W[(kk + wk) * CC + col0 + wc];
        __syncthreads();
#pragma unroll
        for (int k = 0; k < 16; ++k) {
            float4 a = *(const float4*)&As[k][m0];
            float4 b = *(const float4*)&Bs[k][n0];
            acc[0][0] += a.x * b.x; acc[0][1] += a.x * b.y; acc[0][2] += a.x * b.z; acc[0][3] += a.x * b.w;
            acc[1][0] += a.y * b.x; acc[1][1] += a.y * b.y; acc[1][2] += a.y * b.z; acc[1][3] += a.y * b.w;
            acc[2][0] += a.z * b.x; acc[2][1] += a.z * b.y; acc[2][2] += a.z * b.z; acc[2][3] += a.z * b.w;
            acc[3][0] += a.w * b.x; acc[3][1] += a.w * b.y; acc[3][2] += a.w * b.z; acc[3][3] += a.w * b.w;
        }
        __syncthreads();
    }
#pragma unroll
    for (int i = 0; i < 4; ++i) {
        int r = row0 + m0 + i;
        if (r < N) {
            *(float4*)&T[(size_t)r * CC + col0 + n0] =
                make_float4(acc[i][0], acc[i][1], acc[i][2], acc[i][3]);
        }
    }
}

// ---------------------------------------------------------------------------
// acc[rows[i]] += vals[i] * T[cols[i]]   (one wave per nnz, 4 cols/lane)
// ---------------------------------------------------------------------------
__global__ __launch_bounds__(256) void spmm_scatter(const int* __restrict__ rows,
                                                    const int* __restrict__ cols,
                                                    const float* __restrict__ vals,
                                                    const float* __restrict__ T,
                                                    float* __restrict__ acc, int nnz) {
    int i = blockIdx.x * 4 + (threadIdx.x >> 6);
    if (i >= nnz) return;
    int l = threadIdx.x & 63;
    int r = rows[i], c = cols[i];
    float v = vals[i];
    float4 xv = *(const float4*)&T[(size_t)c * CC + l * 4];
    float* dst = acc + (size_t)r * CC + l * 4;
    atomicAdd(dst + 0, v * xv.x);
    atomicAdd(dst + 1, v * xv.y);
    atomicAdd(dst + 2, v * xv.z);
    atomicAdd(dst + 3, v * xv.w);
}

// ---------------------------------------------------------------------------
// per-segment node counts
// ---------------------------------------------------------------------------
__global__ void seg_count(const int* __restrict__ seg, int n, int* __restrict__ cnt) {
    int i = blockIdx.x * 256 + threadIdx.x;
    if (i < n) atomicAdd(cnt + seg[i], 1);
}

// ---------------------------------------------------------------------------
// y = sigmoid(acc) @ linW + b ; pool[seg] += y     (8 nodes per block)
// ---------------------------------------------------------------------------
__global__ __launch_bounds__(256) void head_pool(const float* __restrict__ acc,
                                                 const float* __restrict__ linW,
                                                 const float* __restrict__ linb,
                                                 const int* __restrict__ seg,
                                                 float* __restrict__ pool, int n) {
    __shared__ float hs[8][256];
    __shared__ float part[8][4][64];
    const int t = threadIdx.x;
    const int node0 = blockIdx.x * 8;
#pragma unroll
    for (int nd = 0; nd < 8; ++nd) {
        int node = node0 + nd;
        float a = (node < n) ? acc[(size_t)node * CC + t] : 0.f;
        hs[nd][t] = 1.f / (1.f + __expf(-a));
    }
    __syncthreads();
    const int o = t & 63, s = t >> 6;
    float p[8] = {};
    for (int c = 0; c < 64; ++c) {
        float w = linW[(s * 64 + c) * OUTD + o];
#pragma unroll
        for (int nd = 0; nd < 8; ++nd) p[nd] += hs[nd][s * 64 + c] * w;
    }
#pragma unroll
    for (int nd = 0; nd < 8; ++nd) part[nd][s][o] = p[nd];
    __syncthreads();
#pragma unroll
    for (int rep = 0; rep < 2; ++rep) {
        int idx = rep * 256 + t;
        int nd = idx >> 6, oo = idx & 63;
        int node = node0 + nd;
        if (node < n) {
            float y = part[nd][0][oo] + part[nd][1][oo] + part[nd][2][oo] + part[nd][3][oo] + linb[oo];
            atomicAdd(&pool[seg[node] * OUTD + oo], y);
        }
    }
}

// ---------------------------------------------------------------------------
// out = (pool0/cnt0 + pool1/cnt1 + pool2/cnt2) / 3
// ---------------------------------------------------------------------------
__global__ void finalize(const float* __restrict__ p0, const float* __restrict__ p1,
                         const float* __restrict__ p2, const int* __restrict__ c0,
                         const int* __restrict__ c1, const int* __restrict__ c2,
                         float* __restrict__ out) {
    int i = blockIdx.x * 64 + threadIdx.x;  // 512 total
    int s = i >> 6;
    float m0 = p0[i] / fmaxf((float)c0[s], 1.f);
    float m1 = p1[i] / fmaxf((float)c1[s], 1.f);
    float m2 = p2[i] / fmaxf((float)c2[s], 1.f);
    out[i] = (m0 + m1 + m2) * (1.f / 3.f);
}

// ---------------------------------------------------------------------------
extern "C" void kernel_launch(void* const* d_in, const int* in_sizes, int n_in,
                              void* d_out, int out_size, void* d_ws, size_t ws_size,
                              hipStream_t stream) {
    const float* x0 = (const float*)d_in[0];
    const float* x1 = (const float*)d_in[1];
    const float* x2 = (const float*)d_in[2];
    // COO index bases: inc1=3, inc2=6, inc1t=9, inc2t=12, adj0=15, adju1=18, adjd1=21, adjd2=24
    const int* belong0 = (const int*)d_in[27];
    const int* belong1 = (const int*)d_in[28];
    const int* belong2 = (const int*)d_in[29];
    // W_0_0=30, W_1_0=31, W_0_1=32, W_1_1=33, W_2_1=34, W_1_2=35, W_2_2=36
    // lin0_W=37, lin1_W=38, lin2_W=39, lin0_b=40, lin1_b=41, lin2_b=42

    // workspace layout (floats): T[N1*C] | accbuf[N1*C] | pool0|pool1|pool2 | cnt0|cnt1|cnt2
    float* ws   = (float*)d_ws;
    float* T    = ws;
    float* accb = T + (size_t)NN1 * CC;
    float* pool0 = accb + (size_t)NN1 * CC;
    float* pool1 = pool0 + BB * OUTD;
    float* pool2 = pool1 + BB * OUTD;
    int*   cnt0  = (int*)(pool2 + BB * OUTD);
    int*   cnt1  = cnt0 + BB;
    int*   cnt2  = cnt1 + BB;

    auto gemm = [&](const float* X, int wi, int N) {
        dim3 g((N + 63) / 64, 4);
        gemm_nx256<<<g, 256, 0, stream>>>(X, (const float*)d_in[wi], T, N);
    };
    auto spmm = [&](int ri, int nnz) {
        spmm_scatter<<<(nnz + 3) / 4, 256, 0, stream>>>(
            (const int*)d_in[ri], (const int*)d_in[ri + 1], (const float*)d_in[ri + 2],
            T, accb, nnz);
    };

    // ---- zero accbuf + pools + counts (contiguous region) ----
    {
        long zf = (long)NN1 * CC + 3 * BB * OUTD + 3 * BB;  // floats (cnt as 0-bits)
        zero_kernel<<<2048, 256, 0, stream>>>((float4*)accb, zf / 4);
    }

    // ---- level 0: h0 = sigmoid(adj0@(x0@W00) + inc1@(x1@W10)) ----
    gemm(x0, 30, NN0); spmm(15, in_sizes[15]);
    gemm(x1, 31, NN1); spmm(3, in_sizes[3]);
    seg_count<<<(NN0 + 255) / 256, 256, 0, stream>>>(belong0, NN0, cnt0);
    head_pool<<<(NN0 + 7) / 8, 256, 0, stream>>>(accb, (const float*)d_in[37],
                                                 (const float*)d_in[40], belong0, pool0, NN0);

    // ---- level 1 ----
    zero_kernel<<<2048, 256, 0, stream>>>((float4*)accb, ((long)NN1 * CC) / 4);
    gemm(x0, 32, NN0); spmm(9, in_sizes[9]);
    gemm(x1, 33, NN1); spmm(21, in_sizes[21]); spmm(18, in_sizes[18]);
    gemm(x2, 34, NN2); spmm(6, in_sizes[6]);
    seg_count<<<(NN1 + 255) / 256, 256, 0, stream>>>(belong1, NN1, cnt1);
    head_pool<<<(NN1 + 7) / 8, 256, 0, stream>>>(accb, (const float*)d_in[38],
                                                 (const float*)d_in[41], belong1, pool1, NN1);

    // ---- level 2 ----
    zero_kernel<<<2048, 256, 0, stream>>>((float4*)accb, ((long)NN2 * CC) / 4);
    gemm(x1, 35, NN1); spmm(12, in_sizes[12]);
    gemm(x2, 36, NN2); spmm(24, in_sizes[24]);
    seg_count<<<(NN2 + 255) / 256, 256, 0, stream>>>(belong2, NN2, cnt2);
    head_pool<<<(NN2 + 7) / 8, 256, 0, stream>>>(accb, (const float*)d_in[39],
                                                 (const float*)d_in[42], belong2, pool2, NN2);

    // ---- combine ----
    finalize<<<8, 64, 0, stream>>>(pool0, pool1, pool2, cnt0, cnt1, cnt2, (float*)d_out);
}

// Round 2
// 3491.810 us; speedup vs baseline: 2.0646x; 2.0646x over previous
//
#include <hip/hip_runtime.h>
#include <math.h>

#define NN0 20000
#define NN1 60000
#define NN2 40000
#define CC 256
#define OUTD 64
#define BB 8
#define MAXE 480000   // adjd1+adju1 concat

// ---------------------------------------------------------------------------
__global__ void zero_kernel(float4* __restrict__ p, long n4) {
    long i = (long)blockIdx.x * blockDim.x + threadIdx.x;
    long stride = (long)gridDim.x * blockDim.x;
    for (; i < n4; i += stride) p[i] = make_float4(0.f, 0.f, 0.f, 0.f);
}

// ---------------------------------------------------------------------------
// T = X (N x 256) @ W (256 x 256), fp32, 64x64 tile, 4x4 microtile
// ---------------------------------------------------------------------------
__global__ __launch_bounds__(256) void gemm_nx256(const float* __restrict__ X,
                                                  const float* __restrict__ W,
                                                  float* __restrict__ T, int N) {
    __shared__ float As[16][68];
    __shared__ float Bs[16][64];
    const int t    = threadIdx.x;
    const int row0 = blockIdx.x * 64;
    const int col0 = blockIdx.y * 64;
    const int tx = t & 15, ty = t >> 4;
    const int m0 = ty * 4, n0 = tx * 4;
    const int lr = t >> 2;
    const int lk = (t & 3) * 4;
    const int wk = t >> 4;
    const int wc = (t & 15) * 4;

    int ar = row0 + lr; if (ar > N - 1) ar = N - 1;
    const float* aptr = X + (size_t)ar * CC;

    float acc[4][4] = {};

    for (int kk = 0; kk < CC; kk += 16) {
        float4 av = *(const float4*)(aptr + kk + lk);
        As[lk + 0][lr] = av.x;
        As[lk + 1][lr] = av.y;
        As[lk + 2][lr] = av.z;
        As[lk + 3][lr] = av.w;
        *(float4*)&Bs[wk][wc] = *(const float4*)&W[(kk + wk) * CC + col0 + wc];
        __syncthreads();
#pragma unroll
        for (int k = 0; k < 16; ++k) {
            float4 a = *(const float4*)&As[k][m0];
            float4 b = *(const float4*)&Bs[k][n0];
            acc[0][0] += a.x * b.x; acc[0][1] += a.x * b.y; acc[0][2] += a.x * b.z; acc[0][3] += a.x * b.w;
            acc[1][0] += a.y * b.x; acc[1][1] += a.y * b.y; acc[1][2] += a.y * b.z; acc[1][3] += a.y * b.w;
            acc[2][0] += a.z * b.x; acc[2][1] += a.z * b.y; acc[2][2] += a.z * b.z; acc[2][3] += a.z * b.w;
            acc[3][0] += a.w * b.x; acc[3][1] += a.w * b.y; acc[3][2] += a.w * b.z; acc[3][3] += a.w * b.w;
        }
        __syncthreads();
    }
#pragma unroll
    for (int i = 0; i < 4; ++i) {
        int r = row0 + m0 + i;
        if (r < N) {
            *(float4*)&T[(size_t)r * CC + col0 + n0] =
                make_float4(acc[i][0], acc[i][1], acc[i][2], acc[i][3]);
        }
    }
}

// ---------------------------------------------------------------------------
// CSR build: histogram -> block scan -> top scan -> add -> scatter
// ---------------------------------------------------------------------------
__global__ void hist_rows(const int* __restrict__ rows, int nnz, int* __restrict__ cnt) {
    int i = blockIdx.x * 256 + threadIdx.x;
    if (i < nnz) atomicAdd(&cnt[rows[i]], 1);
}

__global__ __launch_bounds__(256) void scan_blocks(const int* __restrict__ cnt, int n,
                                                   int* __restrict__ localex,
                                                   int* __restrict__ bsum) {
    __shared__ int sm[256];
    int t = threadIdx.x;
    int i = blockIdx.x * 256 + t;
    int v = (i < n) ? cnt[i] : 0;
    sm[t] = v;
    __syncthreads();
    for (int d = 1; d < 256; d <<= 1) {
        int x = (t >= d) ? sm[t - d] : 0;
        __syncthreads();
        sm[t] += x;
        __syncthreads();
    }
    if (i < n) localex[i] = sm[t] - v;          // exclusive within block
    if (t == 255) bsum[blockIdx.x] = sm[255];   // block total
}

__global__ void scan_tops(int* bsum, int nb) {
    if (threadIdx.x == 0 && blockIdx.x == 0) {
        int run = 0;
        for (int i = 0; i < nb; ++i) { int v = bsum[i]; bsum[i] = run; run += v; }
    }
}

__global__ void scan_add(int* __restrict__ rstart, const int* __restrict__ bsum, int n,
                         int* __restrict__ cursor) {
    int i = blockIdx.x * 256 + threadIdx.x;
    if (i < n) {
        int v = rstart[i] + bsum[blockIdx.x];
        rstart[i] = v;
        cursor[i] = v;
    }
}

__global__ void scatter_entries(const int* __restrict__ rows, const int* __restrict__ cols,
                                const float* __restrict__ vals, int nnz,
                                int* __restrict__ cursor, int* __restrict__ eoff,
                                float* __restrict__ eval) {
    int i = blockIdx.x * 256 + threadIdx.x;
    if (i >= nnz) return;
    int p = atomicAdd(&cursor[rows[i]], 1);
    eoff[p] = cols[i] * CC;
    eval[p] = vals[i];
}

// ---------------------------------------------------------------------------
// acc[row] (+)= sum_j eval[j] * T[eoff[j]]   — one wave per row, no atomics
// ---------------------------------------------------------------------------
__global__ __launch_bounds__(256) void spmm_rows(const int* __restrict__ eoff,
                                                 const float* __restrict__ eval,
                                                 const int* __restrict__ rstart,
                                                 const int* __restrict__ rcnt,
                                                 const float* __restrict__ T,
                                                 float* __restrict__ acc,
                                                 int nrows, int accumulate) {
    int row = blockIdx.x * 4 + (threadIdx.x >> 6);
    if (row >= nrows) return;
    int l = threadIdx.x & 63;
    int s = rstart[row], c = rcnt[row];
    float4 a;
    if (accumulate) a = *(const float4*)&acc[(size_t)row * CC + l * 4];
    else            a = make_float4(0.f, 0.f, 0.f, 0.f);
    for (int base = 0; base < c; base += 64) {
        int j = base + l;
        int off = 0; float v = 0.f;
        if (j < c) { off = eoff[s + j]; v = eval[s + j]; }
        int lim = min(64, c - base);
        for (int i = 0; i < lim; ++i) {
            int   ob = __shfl(off, i, 64);
            float vb = __shfl(v,  i, 64);
            float4 x = *(const float4*)&T[(size_t)ob + l * 4];
            a.x += vb * x.x; a.y += vb * x.y; a.z += vb * x.z; a.w += vb * x.w;
        }
    }
    *(float4*)&acc[(size_t)row * CC + l * 4] = a;
}

// ---------------------------------------------------------------------------
// fallback (round-1) atomic scatter
// ---------------------------------------------------------------------------
__global__ __launch_bounds__(256) void spmm_scatter(const int* __restrict__ rows,
                                                    const int* __restrict__ cols,
                                                    const float* __restrict__ vals,
                                                    const float* __restrict__ T,
                                                    float* __restrict__ acc, int nnz) {
    int i = blockIdx.x * 4 + (threadIdx.x >> 6);
    if (i >= nnz) return;
    int l = threadIdx.x & 63;
    int r = rows[i], c = cols[i];
    float v = vals[i];
    float4 xv = *(const float4*)&T[(size_t)c * CC + l * 4];
    float* dst = acc + (size_t)r * CC + l * 4;
    atomicAdd(dst + 0, v * xv.x);
    atomicAdd(dst + 1, v * xv.y);
    atomicAdd(dst + 2, v * xv.z);
    atomicAdd(dst + 3, v * xv.w);
}

// ---------------------------------------------------------------------------
__global__ void seg_count(const int* __restrict__ seg, int n, int* __restrict__ cnt) {
    int i = blockIdx.x * 256 + threadIdx.x;
    if (i < n) atomicAdd(cnt + seg[i], 1);
}

__global__ __launch_bounds__(256) void head_pool(const float* __restrict__ acc,
                                                 const float* __restrict__ linW,
                                                 const float* __restrict__ linb,
                                                 const int* __restrict__ seg,
                                                 float* __restrict__ pool, int n) {
    __shared__ float hs[8][256];
    __shared__ float part[8][4][64];
    const int t = threadIdx.x;
    const int node0 = blockIdx.x * 8;
#pragma unroll
    for (int nd = 0; nd < 8; ++nd) {
        int node = node0 + nd;
        float a = (node < n) ? acc[(size_t)node * CC + t] : 0.f;
        hs[nd][t] = 1.f / (1.f + __expf(-a));
    }
    __syncthreads();
    const int o = t & 63, s = t >> 6;
    float p[8] = {};
    for (int c = 0; c < 64; ++c) {
        float w = linW[(s * 64 + c) * OUTD + o];
#pragma unroll
        for (int nd = 0; nd < 8; ++nd) p[nd] += hs[nd][s * 64 + c] * w;
    }
#pragma unroll
    for (int nd = 0; nd < 8; ++nd) part[nd][s][o] = p[nd];
    __syncthreads();
#pragma unroll
    for (int rep = 0; rep < 2; ++rep) {
        int idx = rep * 256 + t;
        int nd = idx >> 6, oo = idx & 63;
        int node = node0 + nd;
        if (node < n) {
            float y = part[nd][0][oo] + part[nd][1][oo] + part[nd][2][oo] + part[nd][3][oo] + linb[oo];
            atomicAdd(&pool[seg[node] * OUTD + oo], y);
        }
    }
}

__global__ void finalize(const float* __restrict__ p0, const float* __restrict__ p1,
                         const float* __restrict__ p2, const int* __restrict__ c0,
                         const int* __restrict__ c1, const int* __restrict__ c2,
                         float* __restrict__ out) {
    int i = blockIdx.x * 64 + threadIdx.x;
    int s = i >> 6;
    float m0 = p0[i] / fmaxf((float)c0[s], 1.f);
    float m1 = p1[i] / fmaxf((float)c1[s], 1.f);
    float m2 = p2[i] / fmaxf((float)c2[s], 1.f);
    out[i] = (m0 + m1 + m2) * (1.f / 3.f);
}

// ---------------------------------------------------------------------------
extern "C" void kernel_launch(void* const* d_in, const int* in_sizes, int n_in,
                              void* d_out, int out_size, void* d_ws, size_t ws_size,
                              hipStream_t stream) {
    const float* x0 = (const float*)d_in[0];
    const float* x1 = (const float*)d_in[1];
    const float* x2 = (const float*)d_in[2];
    const int* belong0 = (const int*)d_in[27];
    const int* belong1 = (const int*)d_in[28];
    const int* belong2 = (const int*)d_in[29];

    // ---- workspace layout (floats/ints) ----
    float* ws    = (float*)d_ws;
    float* T     = ws;                                 // NN1*CC
    float* accb  = T + (size_t)NN1 * CC;               // NN1*CC
    int*   eoff  = (int*)(accb + (size_t)NN1 * CC);    // MAXE
    float* eval  = (float*)(eoff + MAXE);              // MAXE
    int*   rcnt  = (int*)(eval + MAXE);                // NN1
    int*   rstart= rcnt + NN1;                         // NN1
    int*   cursor= rstart + NN1;                       // NN1
    int*   bsum  = cursor + NN1;                       // 512
    float* pool0 = (float*)(bsum + 512);               // 3*512 + 24 (contiguous zero region)
    float* pool1 = pool0 + BB * OUTD;
    float* pool2 = pool1 + BB * OUTD;
    int*   cnt0  = (int*)(pool2 + BB * OUTD);
    int*   cnt1  = cnt0 + BB;
    int*   cnt2  = cnt1 + BB;
    size_t required = (size_t)((char*)(cnt2 + BB) - (char*)d_ws);

    auto gemm = [&](const float* X, int wi, int N) {
        dim3 g((N + 63) / 64, 4);
        gemm_nx256<<<g, 256, 0, stream>>>(X, (const float*)d_in[wi], T, N);
    };

    if (ws_size >= required) {
        // ================= CSR gather path =================
        auto build2 = [&](int N, int mA, int mB) {  // mB<0 -> single matrix
            int nb = (N + 255) / 256;
            zero_kernel<<<(N / 4 + 255) / 256, 256, 0, stream>>>((float4*)rcnt, N / 4);
            hist_rows<<<(in_sizes[mA] + 255) / 256, 256, 0, stream>>>((const int*)d_in[mA], in_sizes[mA], rcnt);
            if (mB >= 0)
                hist_rows<<<(in_sizes[mB] + 255) / 256, 256, 0, stream>>>((const int*)d_in[mB], in_sizes[mB], rcnt);
            scan_blocks<<<nb, 256, 0, stream>>>(rcnt, N, rstart, bsum);
            scan_tops<<<1, 64, 0, stream>>>(bsum, nb);
            scan_add<<<nb, 256, 0, stream>>>(rstart, bsum, N, cursor);
            scatter_entries<<<(in_sizes[mA] + 255) / 256, 256, 0, stream>>>(
                (const int*)d_in[mA], (const int*)d_in[mA + 1], (const float*)d_in[mA + 2],
                in_sizes[mA], cursor, eoff, eval);
            if (mB >= 0)
                scatter_entries<<<(in_sizes[mB] + 255) / 256, 256, 0, stream>>>(
                    (const int*)d_in[mB], (const int*)d_in[mB + 1], (const float*)d_in[mB + 2],
                    in_sizes[mB], cursor, eoff, eval);
        };
        auto rows = [&](int N, int accum) {
            spmm_rows<<<(N + 3) / 4, 256, 0, stream>>>(eoff, eval, rstart, rcnt, T, accb, N, accum);
        };

        // zero pools + counts (contiguous, 1560 words)
        zero_kernel<<<2, 256, 0, stream>>>((float4*)pool0, (3 * BB * OUTD + 3 * BB) / 4);

        // ---- level 0 ----
        gemm(x0, 30, NN0); build2(NN0, 15, -1); rows(NN0, 0);
        gemm(x1, 31, NN1); build2(NN0, 3, -1);  rows(NN0, 1);
        seg_count<<<(NN0 + 255) / 256, 256, 0, stream>>>(belong0, NN0, cnt0);
        head_pool<<<(NN0 + 7) / 8, 256, 0, stream>>>(accb, (const float*)d_in[37],
                                                     (const float*)d_in[40], belong0, pool0, NN0);
        // ---- level 1 ----
        gemm(x0, 32, NN0); build2(NN1, 9, -1);  rows(NN1, 0);
        gemm(x1, 33, NN1); build2(NN1, 21, 18); rows(NN1, 1);
        gemm(x2, 34, NN2); build2(NN1, 6, -1);  rows(NN1, 1);
        seg_count<<<(NN1 + 255) / 256, 256, 0, stream>>>(belong1, NN1, cnt1);
        head_pool<<<(NN1 + 7) / 8, 256, 0, stream>>>(accb, (const float*)d_in[38],
                                                     (const float*)d_in[41], belong1, pool1, NN1);
        // ---- level 2 ----
        gemm(x1, 35, NN1); build2(NN2, 12, -1); rows(NN2, 0);
        gemm(x2, 36, NN2); build2(NN2, 24, -1); rows(NN2, 1);
        seg_count<<<(NN2 + 255) / 256, 256, 0, stream>>>(belong2, NN2, cnt2);
        head_pool<<<(NN2 + 7) / 8, 256, 0, stream>>>(accb, (const float*)d_in[39],
                                                     (const float*)d_in[42], belong2, pool2, NN2);

        finalize<<<8, 64, 0, stream>>>(pool0, pool1, pool2, cnt0, cnt1, cnt2, (float*)d_out);
    } else {
        // ================= fallback: round-1 atomic path =================
        float* fpool0 = accb + (size_t)NN1 * CC;
        float* fpool1 = fpool0 + BB * OUTD;
        float* fpool2 = fpool1 + BB * OUTD;
        int*   fcnt0  = (int*)(fpool2 + BB * OUTD);
        int*   fcnt1  = fcnt0 + BB;
        int*   fcnt2  = fcnt1 + BB;
        auto spmm = [&](int ri, int nnz) {
            spmm_scatter<<<(nnz + 3) / 4, 256, 0, stream>>>(
                (const int*)d_in[ri], (const int*)d_in[ri + 1], (const float*)d_in[ri + 2],
                T, accb, nnz);
        };
        long zf = (long)NN1 * CC + 3 * BB * OUTD + 3 * BB;
        zero_kernel<<<2048, 256, 0, stream>>>((float4*)accb, zf / 4);
        gemm(x0, 30, NN0); spmm(15, in_sizes[15]);
        gemm(x1, 31, NN1); spmm(3, in_sizes[3]);
        seg_count<<<(NN0 + 255) / 256, 256, 0, stream>>>(belong0, NN0, fcnt0);
        head_pool<<<(NN0 + 7) / 8, 256, 0, stream>>>(accb, (const float*)d_in[37],
                                                     (const float*)d_in[40], belong0, fpool0, NN0);
        zero_kernel<<<2048, 256, 0, stream>>>((float4*)accb, ((long)NN1 * CC) / 4);
        gemm(x0, 32, NN0); spmm(9, in_sizes[9]);
        gemm(x1, 33, NN1); spmm(21, in_sizes[21]); spmm(18, in_sizes[18]);
        gemm(x2, 34, NN2); spmm(6, in_sizes[6]);
        seg_count<<<(NN1 + 255) / 256, 256, 0, stream>>>(belong1, NN1, fcnt1);
        head_pool<<<(NN1 + 7) / 8, 256, 0, stream>>>(accb, (const float*)d_in[38],
                                                     (const float*)d_in[41], belong1, fpool1, NN1);
        zero_kernel<<<2048, 256, 0, stream>>>((float4*)accb, ((long)NN2 * CC) / 4);
        gemm(x1, 35, NN1); spmm(12, in_sizes[12]);
        gemm(x2, 36, NN2); spmm(24, in_sizes[24]);
        seg_count<<<(NN2 + 255) / 256, 256, 0, stream>>>(belong2, NN2, fcnt2);
        head_pool<<<(NN2 + 7) / 8, 256, 0, stream>>>(accb, (const float*)d_in[39],
                                                     (const float*)d_in[42], belong2, fpool2, NN2);
        finalize<<<8, 64, 0, stream>>>(fpool0, fpool1, fpool2, fcnt0, fcnt1, fcnt2, (float*)d_out);
    }
}

// Round 3
// 1449.301 us; speedup vs baseline: 4.9741x; 2.4093x over previous
//
#include <hip/hip_runtime.h>
#include <math.h>

#define NN0 20000
#define NN1 60000
#define NN2 40000
#define CC 256
#define OUTD 64
#define BB 8
#define MAXE 480000   // adjd1+adju1 concat

// ---------------------------------------------------------------------------
__global__ void zero_kernel(float4* __restrict__ p, long n4) {
    long i = (long)blockIdx.x * blockDim.x + threadIdx.x;
    long stride = (long)gridDim.x * blockDim.x;
    for (; i < n4; i += stride) p[i] = make_float4(0.f, 0.f, 0.f, 0.f);
}

// ---------------------------------------------------------------------------
// T = X (N x 256) @ W (256 x 256), fp32, 64x64 tile, 4x4 microtile
// ---------------------------------------------------------------------------
__global__ __launch_bounds__(256) void gemm_nx256(const float* __restrict__ X,
                                                  const float* __restrict__ W,
                                                  float* __restrict__ T, int N) {
    __shared__ float As[16][68];
    __shared__ float Bs[16][64];
    const int t    = threadIdx.x;
    const int row0 = blockIdx.x * 64;
    const int col0 = blockIdx.y * 64;
    const int tx = t & 15, ty = t >> 4;
    const int m0 = ty * 4, n0 = tx * 4;
    const int lr = t >> 2;
    const int lk = (t & 3) * 4;
    const int wk = t >> 4;
    const int wc = (t & 15) * 4;

    int ar = row0 + lr; if (ar > N - 1) ar = N - 1;
    const float* aptr = X + (size_t)ar * CC;

    float acc[4][4] = {};

    for (int kk = 0; kk < CC; kk += 16) {
        float4 av = *(const float4*)(aptr + kk + lk);
        As[lk + 0][lr] = av.x;
        As[lk + 1][lr] = av.y;
        As[lk + 2][lr] = av.z;
        As[lk + 3][lr] = av.w;
        *(float4*)&Bs[wk][wc] = *(const float4*)&W[(kk + wk) * CC + col0 + wc];
        __syncthreads();
#pragma unroll
        for (int k = 0; k < 16; ++k) {
            float4 a = *(const float4*)&As[k][m0];
            float4 b = *(const float4*)&Bs[k][n0];
            acc[0][0] += a.x * b.x; acc[0][1] += a.x * b.y; acc[0][2] += a.x * b.z; acc[0][3] += a.x * b.w;
            acc[1][0] += a.y * b.x; acc[1][1] += a.y * b.y; acc[1][2] += a.y * b.z; acc[1][3] += a.y * b.w;
            acc[2][0] += a.z * b.x; acc[2][1] += a.z * b.y; acc[2][2] += a.z * b.z; acc[2][3] += a.z * b.w;
            acc[3][0] += a.w * b.x; acc[3][1] += a.w * b.y; acc[3][2] += a.w * b.z; acc[3][3] += a.w * b.w;
        }
        __syncthreads();
    }
#pragma unroll
    for (int i = 0; i < 4; ++i) {
        int r = row0 + m0 + i;
        if (r < N) {
            *(float4*)&T[(size_t)r * CC + col0 + n0] =
                make_float4(acc[i][0], acc[i][1], acc[i][2], acc[i][3]);
        }
    }
}

// ---------------------------------------------------------------------------
// CSR build: histogram -> block scan -> top scan -> add -> scatter
// ---------------------------------------------------------------------------
__global__ void hist_rows(const int* __restrict__ rows, int nnz, int* __restrict__ cnt) {
    int i = blockIdx.x * 256 + threadIdx.x;
    if (i < nnz) atomicAdd(&cnt[rows[i]], 1);
}

__global__ __launch_bounds__(256) void scan_blocks(const int* __restrict__ cnt, int n,
                                                   int* __restrict__ localex,
                                                   int* __restrict__ bsum) {
    __shared__ int sm[256];
    int t = threadIdx.x;
    int i = blockIdx.x * 256 + t;
    int v = (i < n) ? cnt[i] : 0;
    sm[t] = v;
    __syncthreads();
    for (int d = 1; d < 256; d <<= 1) {
        int x = (t >= d) ? sm[t - d] : 0;
        __syncthreads();
        sm[t] += x;
        __syncthreads();
    }
    if (i < n) localex[i] = sm[t] - v;
    if (t == 255) bsum[blockIdx.x] = sm[255];
}

__global__ void scan_tops(int* bsum, int nb) {
    if (threadIdx.x == 0 && blockIdx.x == 0) {
        int run = 0;
        for (int i = 0; i < nb; ++i) { int v = bsum[i]; bsum[i] = run; run += v; }
    }
}

__global__ void scan_add(int* __restrict__ rstart, const int* __restrict__ bsum, int n,
                         int* __restrict__ cursor) {
    int i = blockIdx.x * 256 + threadIdx.x;
    if (i < n) {
        int v = rstart[i] + bsum[blockIdx.x];
        rstart[i] = v;
        cursor[i] = v;
    }
}

__global__ void scatter_entries(const int* __restrict__ rows, const int* __restrict__ cols,
                                const float* __restrict__ vals, int nnz,
                                int* __restrict__ cursor, int* __restrict__ eoff,
                                float* __restrict__ eval) {
    int i = blockIdx.x * 256 + threadIdx.x;
    if (i >= nnz) return;
    int p = atomicAdd(&cursor[rows[i]], 1);
    eoff[p] = cols[i] * CC;
    eval[p] = vals[i];
}

// ---------------------------------------------------------------------------
// acc[row] (+)= sum_j eval[j] * T[eoff[j]]   — one wave per row, no atomics
// ---------------------------------------------------------------------------
__global__ __launch_bounds__(256) void spmm_rows(const int* __restrict__ eoff,
                                                 const float* __restrict__ eval,
                                                 const int* __restrict__ rstart,
                                                 const int* __restrict__ rcnt,
                                                 const float* __restrict__ T,
                                                 float* __restrict__ acc,
                                                 int nrows, int accumulate) {
    int row = blockIdx.x * 4 + (threadIdx.x >> 6);
    if (row >= nrows) return;
    int l = threadIdx.x & 63;
    int s = rstart[row], c = rcnt[row];
    float4 a;
    if (accumulate) a = *(const float4*)&acc[(size_t)row * CC + l * 4];
    else            a = make_float4(0.f, 0.f, 0.f, 0.f);
    for (int base = 0; base < c; base += 64) {
        int j = base + l;
        int off = 0; float v = 0.f;
        if (j < c) { off = eoff[s + j]; v = eval[s + j]; }
        int lim = min(64, c - base);
        for (int i = 0; i < lim; ++i) {
            int   ob = __shfl(off, i, 64);
            float vb = __shfl(v,  i, 64);
            float4 x = *(const float4*)&T[(size_t)ob + l * 4];
            a.x += vb * x.x; a.y += vb * x.y; a.z += vb * x.z; a.w += vb * x.w;
        }
    }
    *(float4*)&acc[(size_t)row * CC + l * 4] = a;
}

// ---------------------------------------------------------------------------
// per-segment node counts — wave-ballot reduced (seg values are 0..7)
// ---------------------------------------------------------------------------
__global__ void seg_count(const int* __restrict__ seg, int n, int* __restrict__ cnt) {
    int i = blockIdx.x * 256 + threadIdx.x;
    int s = (i < n) ? seg[i] : -1;
#pragma unroll
    for (int v = 0; v < BB; ++v) {
        unsigned long long m = __ballot(s == v);
        if ((threadIdx.x & 63) == 0 && m)
            atomicAdd(&cnt[v], (int)__popcll(m));
    }
}

// ---------------------------------------------------------------------------
// poolh[seg] += sigmoid(acc[node])  — thread=column, block=64 sorted nodes,
// register run-length accumulate, atomic flush only on segment change
// ---------------------------------------------------------------------------
__global__ __launch_bounds__(256) void pool_sigmoid(const float* __restrict__ acc,
                                                    const int* __restrict__ seg,
                                                    float* __restrict__ poolh, int n) {
    int c = threadIdx.x;
    int node0 = blockIdx.x * 64;
    int nend = min(node0 + 64, n);
    float run = 0.f;
    int curseg = seg[node0];
    for (int node = node0; node < nend; ++node) {
        int s = seg[node];   // wave-uniform -> scalar load
        float a = acc[(size_t)node * CC + c];
        float h = 1.f / (1.f + __expf(-a));
        if (s != curseg) {
            atomicAdd(&poolh[curseg * CC + c], run);
            run = 0.f; curseg = s;
        }
        run += h;
    }
    atomicAdd(&poolh[curseg * CC + c], run);
}

// ---------------------------------------------------------------------------
// out[s*64+o] = ( (ph0[s]/c0)@W0 + b0 + (ph1[s]/c1)@W1 + b1 + (ph2[s]/c2)@W2 + b2 ) / 3
// ---------------------------------------------------------------------------
__global__ __launch_bounds__(64) void final_head(const float* __restrict__ ph0,
                                                 const float* __restrict__ ph1,
                                                 const float* __restrict__ ph2,
                                                 const int* __restrict__ c0,
                                                 const int* __restrict__ c1,
                                                 const int* __restrict__ c2,
                                                 const float* __restrict__ W0,
                                                 const float* __restrict__ W1,
                                                 const float* __restrict__ W2,
                                                 const float* __restrict__ b0,
                                                 const float* __restrict__ b1,
                                                 const float* __restrict__ b2,
                                                 float* __restrict__ out) {
    int s = blockIdx.x, o = threadIdx.x;
    float inv0 = 1.f / fmaxf((float)c0[s], 1.f);
    float inv1 = 1.f / fmaxf((float)c1[s], 1.f);
    float inv2 = 1.f / fmaxf((float)c2[s], 1.f);
    float a0 = 0.f, a1 = 0.f, a2 = 0.f;
    for (int k = 0; k < CC; ++k) {
        a0 += ph0[s * CC + k] * W0[k * OUTD + o];
        a1 += ph1[s * CC + k] * W1[k * OUTD + o];
        a2 += ph2[s * CC + k] * W2[k * OUTD + o];
    }
    out[s * OUTD + o] = (a0 * inv0 + b0[o] + a1 * inv1 + b1[o] + a2 * inv2 + b2[o]) * (1.f / 3.f);
}

// ---------------------------------------------------------------------------
extern "C" void kernel_launch(void* const* d_in, const int* in_sizes, int n_in,
                              void* d_out, int out_size, void* d_ws, size_t ws_size,
                              hipStream_t stream) {
    const float* x0 = (const float*)d_in[0];
    const float* x1 = (const float*)d_in[1];
    const float* x2 = (const float*)d_in[2];
    const int* belong0 = (const int*)d_in[27];
    const int* belong1 = (const int*)d_in[28];
    const int* belong2 = (const int*)d_in[29];

    // ---- workspace layout ----
    float* ws    = (float*)d_ws;
    float* T     = ws;                                 // NN1*CC
    float* accb  = T + (size_t)NN1 * CC;               // NN1*CC
    int*   eoff  = (int*)(accb + (size_t)NN1 * CC);    // MAXE
    float* eval  = (float*)(eoff + MAXE);              // MAXE
    int*   rcnt  = (int*)(eval + MAXE);                // NN1
    int*   rstart= rcnt + NN1;                         // NN1
    int*   cursor= rstart + NN1;                       // NN1
    int*   bsum  = cursor + NN1;                       // 512
    float* ph0   = (float*)(bsum + 512);               // BB*CC  (zero region start)
    float* ph1   = ph0 + BB * CC;
    float* ph2   = ph1 + BB * CC;
    int*   cnt0  = (int*)(ph2 + BB * CC);
    int*   cnt1  = cnt0 + BB;
    int*   cnt2  = cnt1 + BB;

    auto gemm = [&](const float* X, int wi, int N) {
        dim3 g((N + 63) / 64, 4);
        gemm_nx256<<<g, 256, 0, stream>>>(X, (const float*)d_in[wi], T, N);
    };
    auto build2 = [&](int N, int mA, int mB) {  // mB<0 -> single matrix
        int nb = (N + 255) / 256;
        zero_kernel<<<(N / 4 + 255) / 256, 256, 0, stream>>>((float4*)rcnt, N / 4);
        hist_rows<<<(in_sizes[mA] + 255) / 256, 256, 0, stream>>>((const int*)d_in[mA], in_sizes[mA], rcnt);
        if (mB >= 0)
            hist_rows<<<(in_sizes[mB] + 255) / 256, 256, 0, stream>>>((const int*)d_in[mB], in_sizes[mB], rcnt);
        scan_blocks<<<nb, 256, 0, stream>>>(rcnt, N, rstart, bsum);
        scan_tops<<<1, 64, 0, stream>>>(bsum, nb);
        scan_add<<<nb, 256, 0, stream>>>(rstart, bsum, N, cursor);
        scatter_entries<<<(in_sizes[mA] + 255) / 256, 256, 0, stream>>>(
            (const int*)d_in[mA], (const int*)d_in[mA + 1], (const float*)d_in[mA + 2],
            in_sizes[mA], cursor, eoff, eval);
        if (mB >= 0)
            scatter_entries<<<(in_sizes[mB] + 255) / 256, 256, 0, stream>>>(
                (const int*)d_in[mB], (const int*)d_in[mB + 1], (const float*)d_in[mB + 2],
                in_sizes[mB], cursor, eoff, eval);
    };
    auto rows = [&](int N, int accum) {
        spmm_rows<<<(N + 3) / 4, 256, 0, stream>>>(eoff, eval, rstart, rcnt, T, accb, N, accum);
    };

    // zero poolh + counts (contiguous region: 3*BB*CC + 3*BB ints)
    zero_kernel<<<8, 256, 0, stream>>>((float4*)ph0, (3 * BB * CC + 3 * BB) / 4);

    // ---- level 0: h0 = sigmoid(adj0@(x0@W00) + inc1@(x1@W10)) ----
    gemm(x0, 30, NN0); build2(NN0, 15, -1); rows(NN0, 0);
    gemm(x1, 31, NN1); build2(NN0, 3, -1);  rows(NN0, 1);
    seg_count<<<(NN0 + 255) / 256, 256, 0, stream>>>(belong0, NN0, cnt0);
    pool_sigmoid<<<(NN0 + 63) / 64, 256, 0, stream>>>(accb, belong0, ph0, NN0);

    // ---- level 1 ----
    gemm(x0, 32, NN0); build2(NN1, 9, -1);  rows(NN1, 0);
    gemm(x1, 33, NN1); build2(NN1, 21, 18); rows(NN1, 1);
    gemm(x2, 34, NN2); build2(NN1, 6, -1);  rows(NN1, 1);
    seg_count<<<(NN1 + 255) / 256, 256, 0, stream>>>(belong1, NN1, cnt1);
    pool_sigmoid<<<(NN1 + 63) / 64, 256, 0, stream>>>(accb, belong1, ph1, NN1);

    // ---- level 2 ----
    gemm(x1, 35, NN1); build2(NN2, 12, -1); rows(NN2, 0);
    gemm(x2, 36, NN2); build2(NN2, 24, -1); rows(NN2, 1);
    seg_count<<<(NN2 + 255) / 256, 256, 0, stream>>>(belong2, NN2, cnt2);
    pool_sigmoid<<<(NN2 + 63) / 64, 256, 0, stream>>>(accb, belong2, ph2, NN2);

    // ---- combine ----
    final_head<<<BB, 64, 0, stream>>>(ph0, ph1, ph2, cnt0, cnt1, cnt2,
                                      (const float*)d_in[37], (const float*)d_in[38],
                                      (const float*)d_in[39], (const float*)d_in[40],
                                      (const float*)d_in[41], (const float*)d_in[42],
                                      (float*)d_out);
}

// Round 5
// 869.793 us; speedup vs baseline: 8.2882x; 1.6663x over previous
//
#include <hip/hip_runtime.h>
#include <math.h>

#define NN0 20000
#define NN1 60000
#define NN2 40000
#define CC 256
#define OUTD 64
#define BB 8

// counter region offsets (each source padded to multiple of 256 rows)
#define CO_ADJ0   0
#define CO_INC1   20224
#define CO_INC1T  40448
#define CO_ADJ1   100608
#define CO_INC2   160768
#define CO_INC2T  220928
#define CO_ADJD2  261120
#define CTOT      301312   // 1177 * 256
#define NBLK      1177
#define ECAP      1300000

typedef __bf16 bf16x8 __attribute__((ext_vector_type(8)));
typedef float  f32x4  __attribute__((ext_vector_type(4)));

// ---------------------------------------------------------------------------
__global__ void zero_kernel(float4* __restrict__ p, long n4) {
    long i = (long)blockIdx.x * blockDim.x + threadIdx.x;
    long stride = (long)gridDim.x * blockDim.x;
    for (; i < n4; i += stride) p[i] = make_float4(0.f, 0.f, 0.f, 0.f);
}

// ---------------------------------------------------------------------------
// W (256x256 fp32, k-major) -> Wt (n-major bf16), 7 matrices
// ---------------------------------------------------------------------------
struct WTab { const float* w[7]; };
__global__ void convert_w(WTab wt, __bf16* __restrict__ Wt) {
    int b = blockIdx.x;            // 7*256
    int w = b >> 8, n = b & 255;
    int k = threadIdx.x;           // 256
    Wt[((size_t)w * 256 + n) * 256 + k] = (__bf16)wt.w[w][k * 256 + n];
}

// ---------------------------------------------------------------------------
// T = X (M x 256 fp32) @ W -> bf16 T, via MFMA 16x16x32 bf16.
// 128x128 tile per block (256 thr, 4 waves, each wave 64x64 = 4x4 mfma grid).
// LDS granule-major [g][m]: granule g = 8 consecutive k (16B), conflict-free.
// ---------------------------------------------------------------------------
__global__ __launch_bounds__(256) void gemm_bf16(const float* __restrict__ X,
                                                 const __bf16* __restrict__ Wt,
                                                 __bf16* __restrict__ T, int M) {
    __shared__ __bf16 Als[4096];   // 4 granule-rows * 128 m * 8 bf16 = 8 KB
    __shared__ __bf16 Bls[4096];
    const int t = threadIdx.x;
    const int row0 = blockIdx.x * 128;
    const int col0 = blockIdx.y * 128;
    const int lane = t & 63, wave = t >> 6;
    const int q = lane >> 4, lm = lane & 15;
    const int wm = (wave & 1) * 64, wn = (wave >> 1) * 64;

    f32x4 acc[4][4];
    const f32x4 z = {0.f, 0.f, 0.f, 0.f};
#pragma unroll
    for (int i = 0; i < 4; ++i)
#pragma unroll
        for (int j = 0; j < 4; ++j) acc[i][j] = z;

    const int g0 = t >> 7, ms = t & 127;   // staging slot: thread covers g0 and g0+2, row ms
    int arow = row0 + ms; if (arow > M - 1) arow = M - 1;
    const float*  ap = X  + (size_t)arow * CC;
    const __bf16* bp = Wt + (size_t)(col0 + ms) * CC;

    for (int kk = 0; kk < CC; kk += 32) {
#pragma unroll
        for (int s = 0; s < 2; ++s) {
            int g = g0 + s * 2;
            float4 f0 = *(const float4*)(ap + kk + g * 8);
            float4 f1 = *(const float4*)(ap + kk + g * 8 + 4);
            bf16x8 pk;
            pk[0] = (__bf16)f0.x; pk[1] = (__bf16)f0.y; pk[2] = (__bf16)f0.z; pk[3] = (__bf16)f0.w;
            pk[4] = (__bf16)f1.x; pk[5] = (__bf16)f1.y; pk[6] = (__bf16)f1.z; pk[7] = (__bf16)f1.w;
            *(bf16x8*)&Als[(g * 128 + ms) * 8] = pk;
            *(bf16x8*)&Bls[(g * 128 + ms) * 8] = *(const bf16x8*)(bp + kk + g * 8);
        }
        __syncthreads();
        bf16x8 af[4], bfr[4];
#pragma unroll
        for (int i = 0; i < 4; ++i)
            af[i] = *(bf16x8*)&Als[(q * 128 + wm + 16 * i + lm) * 8];
#pragma unroll
        for (int j = 0; j < 4; ++j)
            bfr[j] = *(bf16x8*)&Bls[(q * 128 + wn + 16 * j + lm) * 8];
#pragma unroll
        for (int i = 0; i < 4; ++i)
#pragma unroll
            for (int j = 0; j < 4; ++j)
                acc[i][j] = __builtin_amdgcn_mfma_f32_16x16x32_bf16(af[i], bfr[j], acc[i][j], 0, 0, 0);
        __syncthreads();
    }
    // epilogue: C/D layout col = lane&15, row = quad*4 + reg
#pragma unroll
    for (int i = 0; i < 4; ++i) {
        int gr0 = row0 + wm + 16 * i + q * 4;
#pragma unroll
        for (int r = 0; r < 4; ++r) {
            int grow = gr0 + r;
            if (grow < M) {
                __bf16* dst = T + (size_t)grow * CC + col0 + wn + lm;
#pragma unroll
                for (int j = 0; j < 4; ++j) dst[16 * j] = (__bf16)acc[i][j][r];
            }
        }
    }
}

// ---------------------------------------------------------------------------
// batched CSR build over 8 COO sources
// ---------------------------------------------------------------------------
struct SrcTab {
    const int*   rows[8];
    const int*   cols[8];
    const float* vals[8];
    int pre[9];    // entry prefix
    int coff[8];   // counter-region offset
};

__global__ void hist_all(SrcTab st, int* __restrict__ cnt, int total) {
    int i = blockIdx.x * 256 + threadIdx.x;
    if (i >= total) return;
    int s = 0;
    while (i >= st.pre[s + 1]) ++s;
    int j = i - st.pre[s];
    atomicAdd(&cnt[st.coff[s] + st.rows[s][j]], 1);
}

__global__ __launch_bounds__(256) void scan_blocks(const int* __restrict__ cnt, int n,
                                                   int* __restrict__ localex,
                                                   int* __restrict__ bsum) {
    __shared__ int sm[256];
    int t = threadIdx.x;
    int i = blockIdx.x * 256 + t;
    int v = (i < n) ? cnt[i] : 0;
    sm[t] = v;
    __syncthreads();
    for (int d = 1; d < 256; d <<= 1) {
        int x = (t >= d) ? sm[t - d] : 0;
        __syncthreads();
        sm[t] += x;
        __syncthreads();
    }
    if (i < n) localex[i] = sm[t] - v;
    if (t == 255) bsum[blockIdx.x] = sm[255];
}

__global__ __launch_bounds__(256) void scan_bsum(int* __restrict__ bsum, int nb) {
    __shared__ int sm[256];
    __shared__ int carry;
    int t = threadIdx.x;
    if (t == 0) carry = 0;
    __syncthreads();
    for (int base = 0; base < nb; base += 256) {
        int i = base + t;
        int v = (i < nb) ? bsum[i] : 0;
        sm[t] = v;
        __syncthreads();
        for (int d = 1; d < 256; d <<= 1) {
            int x = (t >= d) ? sm[t - d] : 0;
            __syncthreads();
            sm[t] += x;
            __syncthreads();
        }
        int excl = sm[t] - v + carry;
        if (i < nb) bsum[i] = excl;
        __syncthreads();
        if (t == 255) carry += sm[255];
        __syncthreads();
    }
}

__global__ void scan_add(int* __restrict__ localex, const int* __restrict__ bsum, int n,
                         int* __restrict__ cursor) {
    int i = blockIdx.x * 256 + threadIdx.x;
    if (i < n) {
        int v = localex[i] + bsum[blockIdx.x];
        localex[i] = v;
        cursor[i] = v;
    }
}

__global__ void scatter_all(SrcTab st, int* __restrict__ cursor,
                            int* __restrict__ eoff, float* __restrict__ eval, int total) {
    int i = blockIdx.x * 256 + threadIdx.x;
    if (i >= total) return;
    int s = 0;
    while (i >= st.pre[s + 1]) ++s;
    int j = i - st.pre[s];
    int p = atomicAdd(&cursor[st.coff[s] + st.rows[s][j]], 1);
    eoff[p] = st.cols[s][j];
    eval[p] = st.vals[s][j];
}

// ---------------------------------------------------------------------------
// acc[row] (+)= sum_j eval[j] * T[eoff[j]]   — one wave per row, bf16 T gather,
// 4 columns per lane (64 lanes x 4 = 256)
// ---------------------------------------------------------------------------
__global__ __launch_bounds__(256) void spmm_rows(const int* __restrict__ eoff,
                                                 const float* __restrict__ eval,
                                                 const int* __restrict__ rstart,
                                                 const int* __restrict__ rcnt,
                                                 const __bf16* __restrict__ T,
                                                 float* __restrict__ acc,
                                                 int co, int nrows, int accumulate) {
    int row = blockIdx.x * 4 + (threadIdx.x >> 6);
    if (row >= nrows) return;
    int l = threadIdx.x & 63;
    int s = rstart[co + row], c = rcnt[co + row];
    float* arow = acc + (size_t)row * CC + l * 4;
    float4 a0;
    if (accumulate) a0 = *(float4*)arow;
    else            a0 = make_float4(0.f, 0.f, 0.f, 0.f);
    for (int base = 0; base < c; base += 64) {
        int j = base + l;
        int off = 0; float v = 0.f;
        if (j < c) { off = eoff[s + j]; v = eval[s + j]; }
        int lim = c - base; if (lim > 64) lim = 64;
        for (int i = 0; i < lim; ++i) {
            int   ob = __shfl(off, i, 64);
            float vb = __shfl(v, i, 64);
            const uint2 u = *(const uint2*)((const unsigned short*)T + (size_t)ob * CC + l * 4);
            float e0 = __uint_as_float(u.x << 16), e1 = __uint_as_float(u.x & 0xFFFF0000u);
            float e2 = __uint_as_float(u.y << 16), e3 = __uint_as_float(u.y & 0xFFFF0000u);
            a0.x += vb * e0; a0.y += vb * e1; a0.z += vb * e2; a0.w += vb * e3;
        }
    }
    *(float4*)arow = a0;
}

// ---------------------------------------------------------------------------
__global__ void seg_count(const int* __restrict__ seg, int n, int* __restrict__ cnt) {
    int i = blockIdx.x * 256 + threadIdx.x;
    int s = (i < n) ? seg[i] : -1;
#pragma unroll
    for (int v = 0; v < BB; ++v) {
        unsigned long long m = __ballot(s == v);
        if ((threadIdx.x & 63) == 0 && m)
            atomicAdd(&cnt[v], (int)__popcll(m));
    }
}

__global__ __launch_bounds__(256) void pool_sigmoid(const float* __restrict__ acc,
                                                    const int* __restrict__ seg,
                                                    float* __restrict__ poolh, int n) {
    int c = threadIdx.x;
    int node0 = blockIdx.x * 64;
    int nend = min(node0 + 64, n);
    float run = 0.f;
    int curseg = seg[node0];
    for (int node = node0; node < nend; ++node) {
        int s = seg[node];
        float a = acc[(size_t)node * CC + c];
        float h = 1.f / (1.f + __expf(-a));
        if (s != curseg) {
            atomicAdd(&poolh[curseg * CC + c], run);
            run = 0.f; curseg = s;
        }
        run += h;
    }
    atomicAdd(&poolh[curseg * CC + c], run);
}

__global__ __launch_bounds__(64) void final_head(const float* __restrict__ ph0,
                                                 const float* __restrict__ ph1,
                                                 const float* __restrict__ ph2,
                                                 const int* __restrict__ c0,
                                                 const int* __restrict__ c1,
                                                 const int* __restrict__ c2,
                                                 const float* __restrict__ W0,
                                                 const float* __restrict__ W1,
                                                 const float* __restrict__ W2,
                                                 const float* __restrict__ b0,
                                                 const float* __restrict__ b1,
                                                 const float* __restrict__ b2,
                                                 float* __restrict__ out) {
    int s = blockIdx.x, o = threadIdx.x;
    float inv0 = 1.f / fmaxf((float)c0[s], 1.f);
    float inv1 = 1.f / fmaxf((float)c1[s], 1.f);
    float inv2 = 1.f / fmaxf((float)c2[s], 1.f);
    float a0 = 0.f, a1 = 0.f, a2 = 0.f;
    for (int k = 0; k < CC; ++k) {
        a0 += ph0[s * CC + k] * W0[k * OUTD + o];
        a1 += ph1[s * CC + k] * W1[k * OUTD + o];
        a2 += ph2[s * CC + k] * W2[k * OUTD + o];
    }
    out[s * OUTD + o] = (a0 * inv0 + b0[o] + a1 * inv1 + b1[o] + a2 * inv2 + b2[o]) * (1.f / 3.f);
}

// ---------------------------------------------------------------------------
extern "C" void kernel_launch(void* const* d_in, const int* in_sizes, int n_in,
                              void* d_out, int out_size, void* d_ws, size_t ws_size,
                              hipStream_t stream) {
    const float* x0 = (const float*)d_in[0];
    const float* x1 = (const float*)d_in[1];
    const float* x2 = (const float*)d_in[2];
    const int* belong0 = (const int*)d_in[27];
    const int* belong1 = (const int*)d_in[28];
    const int* belong2 = (const int*)d_in[29];

    // ---- workspace layout (bytes) ----
    char* w = (char*)d_ws;
    __bf16* T    = (__bf16*)w;  w += (size_t)NN1 * CC * 2;   // 30.72 MB
    float*  accb = (float*)w;   w += (size_t)NN1 * CC * 4;   // 61.44 MB
    __bf16* Wt   = (__bf16*)w;  w += (size_t)7 * CC * CC * 2;
    int*    eoff = (int*)w;     w += (size_t)ECAP * 4;
    float*  eval = (float*)w;   w += (size_t)ECAP * 4;
    int*    cnt  = (int*)w;     w += (size_t)CTOT * 4;       // zero-region start
    float*  poolh= (float*)w;   w += 3 * BB * CC * 4;
    int*    segc = (int*)w;     w += 32 * 4;                 // zero-region end
    int*    rstart=(int*)w;     w += (size_t)CTOT * 4;
    int*    cursor=(int*)w;     w += (size_t)CTOT * 4;
    int*    bsum = (int*)w;     w += 2048 * 4;
    int* cnt0 = segc, *cnt1 = segc + 8, *cnt2 = segc + 16;

    // ---- source table (order = consumption order) ----
    const int bases[8] = {15, 3, 9, 21, 18, 6, 12, 24};
    const int coffs[8] = {CO_ADJ0, CO_INC1, CO_INC1T, CO_ADJ1, CO_ADJ1,
                          CO_INC2, CO_INC2T, CO_ADJD2};
    SrcTab st;
    int run = 0;
    for (int s = 0; s < 8; ++s) {
        st.rows[s] = (const int*)d_in[bases[s]];
        st.cols[s] = (const int*)d_in[bases[s] + 1];
        st.vals[s] = (const float*)d_in[bases[s] + 2];
        st.coff[s] = coffs[s];
        st.pre[s] = run;
        run += in_sizes[bases[s]];
    }
    st.pre[8] = run;
    const int total = run;

    WTab wt;
    for (int i = 0; i < 7; ++i) wt.w[i] = (const float*)d_in[30 + i];

    // ---- batched CSR build + weight convert ----
    zero_kernel<<<512, 256, 0, stream>>>((float4*)cnt, (CTOT * 4 + 3 * BB * CC * 4 + 128) / 16);
    hist_all<<<(total + 255) / 256, 256, 0, stream>>>(st, cnt, total);
    convert_w<<<7 * 256, 256, 0, stream>>>(wt, Wt);
    scan_blocks<<<NBLK, 256, 0, stream>>>(cnt, CTOT, rstart, bsum);
    scan_bsum<<<1, 256, 0, stream>>>(bsum, NBLK);
    scan_add<<<NBLK, 256, 0, stream>>>(rstart, bsum, CTOT, cursor);
    scatter_all<<<(total + 255) / 256, 256, 0, stream>>>(st, cursor, eoff, eval, total);

    auto gemm = [&](const float* X, int wi, int M) {
        dim3 g((M + 127) / 128, 2);
        gemm_bf16<<<g, 256, 0, stream>>>(X, Wt + (size_t)wi * CC * CC, T, M);
    };
    auto spmm = [&](int co, int nrows, int accum) {
        spmm_rows<<<(nrows + 3) / 4, 256, 0, stream>>>(eoff, eval, rstart, cnt, T, accb,
                                                       co, nrows, accum);
    };

    // ---- level 0: h0 = sigmoid(adj0@(x0@W00) + inc1@(x1@W10)) ----
    gemm(x0, 0, NN0); spmm(CO_ADJ0, NN0, 0);
    gemm(x1, 1, NN1); spmm(CO_INC1, NN0, 1);
    seg_count<<<(NN0 + 255) / 256, 256, 0, stream>>>(belong0, NN0, cnt0);
    pool_sigmoid<<<(NN0 + 63) / 64, 256, 0, stream>>>(accb, belong0, poolh, NN0);

    // ---- level 1 ----
    gemm(x0, 2, NN0); spmm(CO_INC1T, NN1, 0);
    gemm(x1, 3, NN1); spmm(CO_ADJ1, NN1, 1);
    gemm(x2, 4, NN2); spmm(CO_INC2, NN1, 1);
    seg_count<<<(NN1 + 255) / 256, 256, 0, stream>>>(belong1, NN1, cnt1);
    pool_sigmoid<<<(NN1 + 63) / 64, 256, 0, stream>>>(accb, belong1, poolh + BB * CC, NN1);

    // ---- level 2 ----
    gemm(x1, 5, NN1); spmm(CO_INC2T, NN2, 0);
    gemm(x2, 6, NN2); spmm(CO_ADJD2, NN2, 1);
    seg_count<<<(NN2 + 255) / 256, 256, 0, stream>>>(belong2, NN2, cnt2);
    pool_sigmoid<<<(NN2 + 63) / 64, 256, 0, stream>>>(accb, belong2, poolh + 2 * BB * CC, NN2);

    // ---- combine ----
    final_head<<<BB, 64, 0, stream>>>(poolh, poolh + BB * CC, poolh + 2 * BB * CC,
                                      cnt0, cnt1, cnt2,
                                      (const float*)d_in[37], (const float*)d_in[38],
                                      (const float*)d_in[39], (const float*)d_in[40],
                                      (const float*)d_in[41], (const float*)d_in[42],
                                      (float*)d_out);
}

// Round 6
// 852.349 us; speedup vs baseline: 8.4578x; 1.0205x over previous
//
#include <hip/hip_runtime.h>
#include <math.h>

#define NN0 20000
#define NN1 60000
#define NN2 40000
#define CC 256
#define OUTD 64
#define BB 8

// counter region offsets (each source padded to multiple of 256 rows)
#define CO_ADJ0   0
#define CO_INC1   20224
#define CO_INC1T  40448
#define CO_ADJ1   100608
#define CO_INC2   160768
#define CO_INC2T  220928
#define CO_ADJD2  261120
#define CTOT      301312   // 1177 * 256
#define NBLK      1177
#define ECAP      1300000

typedef __bf16 bf16x8 __attribute__((ext_vector_type(8)));
typedef float  f32x4  __attribute__((ext_vector_type(4)));

// ---------------------------------------------------------------------------
__global__ void zero_kernel(float4* __restrict__ p, long n4) {
    long i = (long)blockIdx.x * blockDim.x + threadIdx.x;
    long stride = (long)gridDim.x * blockDim.x;
    for (; i < n4; i += stride) p[i] = make_float4(0.f, 0.f, 0.f, 0.f);
}

// ---------------------------------------------------------------------------
// W (256x256 fp32, k-major) -> Wt (n-major bf16), 7 matrices
// ---------------------------------------------------------------------------
struct WTab { const float* w[7]; };
__global__ void convert_w(WTab wt, __bf16* __restrict__ Wt) {
    int b = blockIdx.x;            // 7*256
    int w = b >> 8, n = b & 255;
    int k = threadIdx.x;           // 256
    Wt[((size_t)w * 256 + n) * 256 + k] = (__bf16)wt.w[w][k * 256 + n];
}

// ---------------------------------------------------------------------------
// T = X (M x 256 fp32) @ W -> bf16 T, via MFMA 16x16x32 bf16.
// 128x128 tile per block (256 thr, 4 waves, each wave 64x64 = 4x4 mfma grid).
// ---------------------------------------------------------------------------
__global__ __launch_bounds__(256) void gemm_bf16(const float* __restrict__ X,
                                                 const __bf16* __restrict__ Wt,
                                                 __bf16* __restrict__ T, int M) {
    __shared__ __bf16 Als[4096];
    __shared__ __bf16 Bls[4096];
    const int t = threadIdx.x;
    const int row0 = blockIdx.x * 128;
    const int col0 = blockIdx.y * 128;
    const int lane = t & 63, wave = t >> 6;
    const int q = lane >> 4, lm = lane & 15;
    const int wm = (wave & 1) * 64, wn = (wave >> 1) * 64;

    f32x4 acc[4][4];
    const f32x4 z = {0.f, 0.f, 0.f, 0.f};
#pragma unroll
    for (int i = 0; i < 4; ++i)
#pragma unroll
        for (int j = 0; j < 4; ++j) acc[i][j] = z;

    const int g0 = t >> 7, ms = t & 127;
    int arow = row0 + ms; if (arow > M - 1) arow = M - 1;
    const float*  ap = X  + (size_t)arow * CC;
    const __bf16* bp = Wt + (size_t)(col0 + ms) * CC;

    for (int kk = 0; kk < CC; kk += 32) {
#pragma unroll
        for (int s = 0; s < 2; ++s) {
            int g = g0 + s * 2;
            float4 f0 = *(const float4*)(ap + kk + g * 8);
            float4 f1 = *(const float4*)(ap + kk + g * 8 + 4);
            bf16x8 pk;
            pk[0] = (__bf16)f0.x; pk[1] = (__bf16)f0.y; pk[2] = (__bf16)f0.z; pk[3] = (__bf16)f0.w;
            pk[4] = (__bf16)f1.x; pk[5] = (__bf16)f1.y; pk[6] = (__bf16)f1.z; pk[7] = (__bf16)f1.w;
            *(bf16x8*)&Als[(g * 128 + ms) * 8] = pk;
            *(bf16x8*)&Bls[(g * 128 + ms) * 8] = *(const bf16x8*)(bp + kk + g * 8);
        }
        __syncthreads();
        bf16x8 af[4], bfr[4];
#pragma unroll
        for (int i = 0; i < 4; ++i)
            af[i] = *(bf16x8*)&Als[(q * 128 + wm + 16 * i + lm) * 8];
#pragma unroll
        for (int j = 0; j < 4; ++j)
            bfr[j] = *(bf16x8*)&Bls[(q * 128 + wn + 16 * j + lm) * 8];
#pragma unroll
        for (int i = 0; i < 4; ++i)
#pragma unroll
            for (int j = 0; j < 4; ++j)
                acc[i][j] = __builtin_amdgcn_mfma_f32_16x16x32_bf16(af[i], bfr[j], acc[i][j], 0, 0, 0);
        __syncthreads();
    }
#pragma unroll
    for (int i = 0; i < 4; ++i) {
        int gr0 = row0 + wm + 16 * i + q * 4;
#pragma unroll
        for (int r = 0; r < 4; ++r) {
            int grow = gr0 + r;
            if (grow < M) {
                __bf16* dst = T + (size_t)grow * CC + col0 + wn + lm;
#pragma unroll
                for (int j = 0; j < 4; ++j) dst[16 * j] = (__bf16)acc[i][j][r];
            }
        }
    }
}

// ---------------------------------------------------------------------------
// batched CSR build over 8 COO sources
// ---------------------------------------------------------------------------
struct SrcTab {
    const int*   rows[8];
    const int*   cols[8];
    const float* vals[8];
    int pre[9];
    int coff[8];
};

__global__ void hist_all(SrcTab st, int* __restrict__ cnt, int total) {
    int i = blockIdx.x * 256 + threadIdx.x;
    if (i >= total) return;
    int s = 0;
    while (i >= st.pre[s + 1]) ++s;
    int j = i - st.pre[s];
    atomicAdd(&cnt[st.coff[s] + st.rows[s][j]], 1);
}

__global__ __launch_bounds__(256) void scan_blocks(const int* __restrict__ cnt, int n,
                                                   int* __restrict__ localex,
                                                   int* __restrict__ bsum) {
    __shared__ int sm[256];
    int t = threadIdx.x;
    int i = blockIdx.x * 256 + t;
    int v = (i < n) ? cnt[i] : 0;
    sm[t] = v;
    __syncthreads();
    for (int d = 1; d < 256; d <<= 1) {
        int x = (t >= d) ? sm[t - d] : 0;
        __syncthreads();
        sm[t] += x;
        __syncthreads();
    }
    if (i < n) localex[i] = sm[t] - v;
    if (t == 255) bsum[blockIdx.x] = sm[255];
}

__global__ __launch_bounds__(256) void scan_bsum(int* __restrict__ bsum, int nb) {
    __shared__ int sm[256];
    __shared__ int carry;
    int t = threadIdx.x;
    if (t == 0) carry = 0;
    __syncthreads();
    for (int base = 0; base < nb; base += 256) {
        int i = base + t;
        int v = (i < nb) ? bsum[i] : 0;
        sm[t] = v;
        __syncthreads();
        for (int d = 1; d < 256; d <<= 1) {
            int x = (t >= d) ? sm[t - d] : 0;
            __syncthreads();
            sm[t] += x;
            __syncthreads();
        }
        int excl = sm[t] - v + carry;
        if (i < nb) bsum[i] = excl;
        __syncthreads();
        if (t == 255) carry += sm[255];
        __syncthreads();
    }
}

__global__ void scan_add(int* __restrict__ localex, const int* __restrict__ bsum, int n,
                         int* __restrict__ cursor) {
    int i = blockIdx.x * 256 + threadIdx.x;
    if (i < n) {
        int v = localex[i] + bsum[blockIdx.x];
        localex[i] = v;
        cursor[i] = v;
    }
}

// packed (col, val-bits) single 8B store per entry
__global__ void scatter_all(SrcTab st, int* __restrict__ cursor,
                            int2* __restrict__ epair, int total) {
    int i = blockIdx.x * 256 + threadIdx.x;
    if (i >= total) return;
    int s = 0;
    while (i >= st.pre[s + 1]) ++s;
    int j = i - st.pre[s];
    int p = atomicAdd(&cursor[st.coff[s] + st.rows[s][j]], 1);
    epair[p] = make_int2(st.cols[s][j], __float_as_int(st.vals[s][j]));
}

// ---------------------------------------------------------------------------
// acc[row] (+)= sum_j val[j] * T[col[j]] — one wave per row, 4 cols/lane,
// inner loop software-pipelined x4 (4 outstanding 512B gathers)
// ---------------------------------------------------------------------------
__global__ __launch_bounds__(256) void spmm_rows(const int2* __restrict__ epair,
                                                 const int* __restrict__ rstart,
                                                 const int* __restrict__ rcnt,
                                                 const __bf16* __restrict__ T,
                                                 float* __restrict__ acc,
                                                 int co, int nrows, int accumulate) {
    int row = blockIdx.x * 4 + (threadIdx.x >> 6);
    if (row >= nrows) return;
    int l = threadIdx.x & 63;
    int s = rstart[co + row], c = rcnt[co + row];
    const unsigned short* Tb = (const unsigned short*)T + l * 4;
    float* arow = acc + (size_t)row * CC + l * 4;
    float4 a0;
    if (accumulate) a0 = *(float4*)arow;
    else            a0 = make_float4(0.f, 0.f, 0.f, 0.f);
    for (int base = 0; base < c; base += 64) {
        int j = base + l;
        int off = 0; float v = 0.f;
        if (j < c) { int2 e = epair[s + j]; off = e.x; v = __int_as_float(e.y); }
        int lim = c - base; if (lim > 64) lim = 64;
        int i = 0;
        for (; i + 4 <= lim; i += 4) {
            int   ob0 = __shfl(off, i,     64), ob1 = __shfl(off, i + 1, 64);
            int   ob2 = __shfl(off, i + 2, 64), ob3 = __shfl(off, i + 3, 64);
            float vb0 = __shfl(v,   i,     64), vb1 = __shfl(v,   i + 1, 64);
            float vb2 = __shfl(v,   i + 2, 64), vb3 = __shfl(v,   i + 3, 64);
            uint2 u0 = *(const uint2*)(Tb + (size_t)ob0 * CC);
            uint2 u1 = *(const uint2*)(Tb + (size_t)ob1 * CC);
            uint2 u2 = *(const uint2*)(Tb + (size_t)ob2 * CC);
            uint2 u3 = *(const uint2*)(Tb + (size_t)ob3 * CC);
            a0.x += vb0 * __uint_as_float(u0.x << 16);
            a0.y += vb0 * __uint_as_float(u0.x & 0xFFFF0000u);
            a0.z += vb0 * __uint_as_float(u0.y << 16);
            a0.w += vb0 * __uint_as_float(u0.y & 0xFFFF0000u);
            a0.x += vb1 * __uint_as_float(u1.x << 16);
            a0.y += vb1 * __uint_as_float(u1.x & 0xFFFF0000u);
            a0.z += vb1 * __uint_as_float(u1.y << 16);
            a0.w += vb1 * __uint_as_float(u1.y & 0xFFFF0000u);
            a0.x += vb2 * __uint_as_float(u2.x << 16);
            a0.y += vb2 * __uint_as_float(u2.x & 0xFFFF0000u);
            a0.z += vb2 * __uint_as_float(u2.y << 16);
            a0.w += vb2 * __uint_as_float(u2.y & 0xFFFF0000u);
            a0.x += vb3 * __uint_as_float(u3.x << 16);
            a0.y += vb3 * __uint_as_float(u3.x & 0xFFFF0000u);
            a0.z += vb3 * __uint_as_float(u3.y << 16);
            a0.w += vb3 * __uint_as_float(u3.y & 0xFFFF0000u);
        }
        for (; i < lim; ++i) {
            int   ob = __shfl(off, i, 64);
            float vb = __shfl(v, i, 64);
            uint2 u = *(const uint2*)(Tb + (size_t)ob * CC);
            a0.x += vb * __uint_as_float(u.x << 16);
            a0.y += vb * __uint_as_float(u.x & 0xFFFF0000u);
            a0.z += vb * __uint_as_float(u.y << 16);
            a0.w += vb * __uint_as_float(u.y & 0xFFFF0000u);
        }
    }
    *(float4*)arow = a0;
}

// ---------------------------------------------------------------------------
// all three belong arrays in one launch (ballot-reduced)
// ---------------------------------------------------------------------------
__global__ void seg_count_all(const int* __restrict__ s0, const int* __restrict__ s1,
                              const int* __restrict__ s2, int* __restrict__ cnt) {
    int i = blockIdx.x * 256 + threadIdx.x;
    int a = (i < NN0) ? s0[i] : -1;
    int b = (i < NN1) ? s1[i] : -1;
    int c = (i < NN2) ? s2[i] : -1;
#pragma unroll
    for (int v = 0; v < BB; ++v) {
        unsigned long long m0 = __ballot(a == v);
        unsigned long long m1 = __ballot(b == v);
        unsigned long long m2 = __ballot(c == v);
        if ((threadIdx.x & 63) == 0) {
            if (m0) atomicAdd(&cnt[v], (int)__popcll(m0));
            if (m1) atomicAdd(&cnt[8 + v], (int)__popcll(m1));
            if (m2) atomicAdd(&cnt[16 + v], (int)__popcll(m2));
        }
    }
}

__global__ __launch_bounds__(256) void pool_sigmoid(const float* __restrict__ acc,
                                                    const int* __restrict__ seg,
                                                    float* __restrict__ poolh, int n) {
    int c = threadIdx.x;
    int node0 = blockIdx.x * 64;
    int nend = min(node0 + 64, n);
    float run = 0.f;
    int curseg = seg[node0];
    for (int node = node0; node < nend; ++node) {
        int s = seg[node];
        float a = acc[(size_t)node * CC + c];
        float h = 1.f / (1.f + __expf(-a));
        if (s != curseg) {
            atomicAdd(&poolh[curseg * CC + c], run);
            run = 0.f; curseg = s;
        }
        run += h;
    }
    atomicAdd(&poolh[curseg * CC + c], run);
}

__global__ __launch_bounds__(64) void final_head(const float* __restrict__ ph0,
                                                 const float* __restrict__ ph1,
                                                 const float* __restrict__ ph2,
                                                 const int* __restrict__ c0,
                                                 const int* __restrict__ c1,
                                                 const int* __restrict__ c2,
                                                 const float* __restrict__ W0,
                                                 const float* __restrict__ W1,
                                                 const float* __restrict__ W2,
                                                 const float* __restrict__ b0,
                                                 const float* __restrict__ b1,
                                                 const float* __restrict__ b2,
                                                 float* __restrict__ out) {
    int s = blockIdx.x, o = threadIdx.x;
    float inv0 = 1.f / fmaxf((float)c0[s], 1.f);
    float inv1 = 1.f / fmaxf((float)c1[s], 1.f);
    float inv2 = 1.f / fmaxf((float)c2[s], 1.f);
    float a0 = 0.f, a1 = 0.f, a2 = 0.f;
    for (int k = 0; k < CC; ++k) {
        a0 += ph0[s * CC + k] * W0[k * OUTD + o];
        a1 += ph1[s * CC + k] * W1[k * OUTD + o];
        a2 += ph2[s * CC + k] * W2[k * OUTD + o];
    }
    out[s * OUTD + o] = (a0 * inv0 + b0[o] + a1 * inv1 + b1[o] + a2 * inv2 + b2[o]) * (1.f / 3.f);
}

// ---------------------------------------------------------------------------
extern "C" void kernel_launch(void* const* d_in, const int* in_sizes, int n_in,
                              void* d_out, int out_size, void* d_ws, size_t ws_size,
                              hipStream_t stream) {
    const float* x0 = (const float*)d_in[0];
    const float* x1 = (const float*)d_in[1];
    const float* x2 = (const float*)d_in[2];
    const int* belong0 = (const int*)d_in[27];
    const int* belong1 = (const int*)d_in[28];
    const int* belong2 = (const int*)d_in[29];

    // ---- workspace layout (bytes) ----
    char* w = (char*)d_ws;
    __bf16* T    = (__bf16*)w;  w += (size_t)NN1 * CC * 2;
    float*  accb = (float*)w;   w += (size_t)NN1 * CC * 4;
    __bf16* Wt   = (__bf16*)w;  w += (size_t)7 * CC * CC * 2;
    int2*   epair= (int2*)w;    w += (size_t)ECAP * 8;
    int*    cnt  = (int*)w;     w += (size_t)CTOT * 4;       // zero-region start
    float*  poolh= (float*)w;   w += 3 * BB * CC * 4;
    int*    segc = (int*)w;     w += 32 * 4;                 // zero-region end
    int*    rstart=(int*)w;     w += (size_t)CTOT * 4;
    int*    cursor=(int*)w;     w += (size_t)CTOT * 4;
    int*    bsum = (int*)w;     w += 2048 * 4;
    int* cnt0 = segc, *cnt1 = segc + 8, *cnt2 = segc + 16;

    // ---- source table ----
    const int bases[8] = {15, 3, 9, 21, 18, 6, 12, 24};
    const int coffs[8] = {CO_ADJ0, CO_INC1, CO_INC1T, CO_ADJ1, CO_ADJ1,
                          CO_INC2, CO_INC2T, CO_ADJD2};
    SrcTab st;
    int run = 0;
    for (int s = 0; s < 8; ++s) {
        st.rows[s] = (const int*)d_in[bases[s]];
        st.cols[s] = (const int*)d_in[bases[s] + 1];
        st.vals[s] = (const float*)d_in[bases[s] + 2];
        st.coff[s] = coffs[s];
        st.pre[s] = run;
        run += in_sizes[bases[s]];
    }
    st.pre[8] = run;
    const int total = run;

    WTab wt;
    for (int i = 0; i < 7; ++i) wt.w[i] = (const float*)d_in[30 + i];

    // ---- batched CSR build + weight convert + seg counts ----
    zero_kernel<<<512, 256, 0, stream>>>((float4*)cnt, (CTOT * 4 + 3 * BB * CC * 4 + 128) / 16);
    hist_all<<<(total + 255) / 256, 256, 0, stream>>>(st, cnt, total);
    convert_w<<<7 * 256, 256, 0, stream>>>(wt, Wt);
    seg_count_all<<<(NN1 + 255) / 256, 256, 0, stream>>>(belong0, belong1, belong2, segc);
    scan_blocks<<<NBLK, 256, 0, stream>>>(cnt, CTOT, rstart, bsum);
    scan_bsum<<<1, 256, 0, stream>>>(bsum, NBLK);
    scan_add<<<NBLK, 256, 0, stream>>>(rstart, bsum, CTOT, cursor);
    scatter_all<<<(total + 255) / 256, 256, 0, stream>>>(st, cursor, epair, total);

    auto gemm = [&](const float* X, int wi, int M) {
        dim3 g((M + 127) / 128, 2);
        gemm_bf16<<<g, 256, 0, stream>>>(X, Wt + (size_t)wi * CC * CC, T, M);
    };
    auto spmm = [&](int co, int nrows, int accum) {
        spmm_rows<<<(nrows + 3) / 4, 256, 0, stream>>>(epair, rstart, cnt, T, accb,
                                                       co, nrows, accum);
    };

    // ---- level 0 ----
    gemm(x0, 0, NN0); spmm(CO_ADJ0, NN0, 0);
    gemm(x1, 1, NN1); spmm(CO_INC1, NN0, 1);
    pool_sigmoid<<<(NN0 + 63) / 64, 256, 0, stream>>>(accb, belong0, poolh, NN0);

    // ---- level 1 ----
    gemm(x0, 2, NN0); spmm(CO_INC1T, NN1, 0);
    gemm(x1, 3, NN1); spmm(CO_ADJ1, NN1, 1);
    gemm(x2, 4, NN2); spmm(CO_INC2, NN1, 1);
    pool_sigmoid<<<(NN1 + 63) / 64, 256, 0, stream>>>(accb, belong1, poolh + BB * CC, NN1);

    // ---- level 2 ----
    gemm(x1, 5, NN1); spmm(CO_INC2T, NN2, 0);
    gemm(x2, 6, NN2); spmm(CO_ADJD2, NN2, 1);
    pool_sigmoid<<<(NN2 + 63) / 64, 256, 0, stream>>>(accb, belong2, poolh + 2 * BB * CC, NN2);

    // ---- combine ----
    final_head<<<BB, 64, 0, stream>>>(poolh, poolh + BB * CC, poolh + 2 * BB * CC,
                                      cnt0, cnt1, cnt2,
                                      (const float*)d_in[37], (const float*)d_in[38],
                                      (const float*)d_in[39], (const float*)d_in[40],
                                      (const float*)d_in[41], (const float*)d_in[42],
                                      (float*)d_out);
}

// Round 7
// 729.142 us; speedup vs baseline: 9.8870x; 1.1690x over previous
//
#include <hip/hip_runtime.h>
#include <math.h>

#define NN0 20000
#define NN1 60000
#define NN2 40000
#define CC 256
#define OUTD 64
#define BB 8

// key space: L0 = row*2+slot in [0,40000); L1 = 40000+row*3+slot; L2 = 220000+row*2+slot
#define KB_L0 0
#define KB_L1 40000
#define KB_L2 220000
#define KTOT  300000
#define CTOT  300288      // 1173 * 256 (padded; pad counters stay 0)
#define NBLK  1173
#define ECAP  1300000

typedef __bf16 bf16x8 __attribute__((ext_vector_type(8)));
typedef __bf16 bf16x4 __attribute__((ext_vector_type(4)));
typedef float  f32x4  __attribute__((ext_vector_type(4)));

// ---------------------------------------------------------------------------
__global__ void zero_kernel(float4* __restrict__ p, long n4) {
    long i = (long)blockIdx.x * blockDim.x + threadIdx.x;
    long stride = (long)gridDim.x * blockDim.x;
    for (; i < n4; i += stride) p[i] = make_float4(0.f, 0.f, 0.f, 0.f);
}

// ---------------------------------------------------------------------------
struct WTab { const float* w[7]; };
__global__ void convert_w(WTab wt, __bf16* __restrict__ Wt) {
    int b = blockIdx.x;            // 7*256
    int w = b >> 8, n = b & 255;
    int k = threadIdx.x;           // 256
    Wt[((size_t)w * 256 + n) * 256 + k] = (__bf16)wt.w[w][k * 256 + n];
}

// ---------------------------------------------------------------------------
// batched GEMM: per level, jobs {X, wIdx, rowBase, M}; T row-block per job.
// 128x128 tile, 4 waves x (4x4) mfma_f32_16x16x32_bf16.
// ---------------------------------------------------------------------------
struct GemmJob { const float* X; int wIdx; int rowBase; int M; };
struct GemmTab { GemmJob j[3]; };

__global__ __launch_bounds__(256) void gemm_level(GemmTab tab,
                                                  const __bf16* __restrict__ WtAll,
                                                  __bf16* __restrict__ T) {
    const GemmJob job = tab.j[blockIdx.z];
    const int row0 = blockIdx.x * 128;
    if (row0 >= job.M) return;
    const int M = job.M;
    const float* __restrict__ X = job.X;
    const __bf16* __restrict__ Wt = WtAll + (size_t)job.wIdx * CC * CC;

    __shared__ __bf16 Als[4096];
    __shared__ __bf16 Bls[4096];
    const int t = threadIdx.x;
    const int col0 = blockIdx.y * 128;
    const int lane = t & 63, wave = t >> 6;
    const int q = lane >> 4, lm = lane & 15;
    const int wm = (wave & 1) * 64, wn = (wave >> 1) * 64;

    f32x4 acc[4][4];
    const f32x4 z = {0.f, 0.f, 0.f, 0.f};
#pragma unroll
    for (int i = 0; i < 4; ++i)
#pragma unroll
        for (int j = 0; j < 4; ++j) acc[i][j] = z;

    const int g0 = t >> 7, ms = t & 127;
    int arow = row0 + ms; if (arow > M - 1) arow = M - 1;
    const float*  ap = X  + (size_t)arow * CC;
    const __bf16* bp = Wt + (size_t)(col0 + ms) * CC;

    for (int kk = 0; kk < CC; kk += 32) {
#pragma unroll
        for (int s = 0; s < 2; ++s) {
            int g = g0 + s * 2;
            float4 f0 = *(const float4*)(ap + kk + g * 8);
            float4 f1 = *(const float4*)(ap + kk + g * 8 + 4);
            bf16x8 pk;
            pk[0] = (__bf16)f0.x; pk[1] = (__bf16)f0.y; pk[2] = (__bf16)f0.z; pk[3] = (__bf16)f0.w;
            pk[4] = (__bf16)f1.x; pk[5] = (__bf16)f1.y; pk[6] = (__bf16)f1.z; pk[7] = (__bf16)f1.w;
            *(bf16x8*)&Als[(g * 128 + ms) * 8] = pk;
            *(bf16x8*)&Bls[(g * 128 + ms) * 8] = *(const bf16x8*)(bp + kk + g * 8);
        }
        __syncthreads();
        bf16x8 af[4], bfr[4];
#pragma unroll
        for (int i = 0; i < 4; ++i)
            af[i] = *(bf16x8*)&Als[(q * 128 + wm + 16 * i + lm) * 8];
#pragma unroll
        for (int j = 0; j < 4; ++j)
            bfr[j] = *(bf16x8*)&Bls[(q * 128 + wn + 16 * j + lm) * 8];
#pragma unroll
        for (int i = 0; i < 4; ++i)
#pragma unroll
            for (int j = 0; j < 4; ++j)
                acc[i][j] = __builtin_amdgcn_mfma_f32_16x16x32_bf16(af[i], bfr[j], acc[i][j], 0, 0, 0);
        __syncthreads();
    }
#pragma unroll
    for (int i = 0; i < 4; ++i) {
        int gr0 = row0 + wm + 16 * i + q * 4;
#pragma unroll
        for (int r = 0; r < 4; ++r) {
            int grow = gr0 + r;
            if (grow < M) {
                __bf16* dst = T + (size_t)(job.rowBase + grow) * CC + col0 + wn + lm;
#pragma unroll
                for (int j = 0; j < 4; ++j) dst[16 * j] = (__bf16)acc[i][j][r];
            }
        }
    }
}

// ---------------------------------------------------------------------------
// batched CSR build over 8 COO sources, level-fused keys
// ---------------------------------------------------------------------------
struct SrcTab {
    const int*   rows[8];
    const int*   cols[8];
    const float* vals[8];
    int pre[9];     // entry prefix
    int kbase[8];   // level key base
    int mulS[8];    // slots per row in this level
    int slot[8];    // slot within row
    int tbase[8];   // T row-base folded into stored col
};

__global__ void hist_all(SrcTab st, int* __restrict__ cnt, int total) {
    int i = blockIdx.x * 256 + threadIdx.x;
    if (i >= total) return;
    int s = 0;
    while (i >= st.pre[s + 1]) ++s;
    int j = i - st.pre[s];
    int key = st.kbase[s] + st.rows[s][j] * st.mulS[s] + st.slot[s];
    atomicAdd(&cnt[key], 1);
}

__global__ __launch_bounds__(256) void scan_blocks(const int* __restrict__ cnt, int n,
                                                   int* __restrict__ localex,
                                                   int* __restrict__ bsum) {
    __shared__ int sm[256];
    int t = threadIdx.x;
    int i = blockIdx.x * 256 + t;
    int v = (i < n) ? cnt[i] : 0;
    sm[t] = v;
    __syncthreads();
    for (int d = 1; d < 256; d <<= 1) {
        int x = (t >= d) ? sm[t - d] : 0;
        __syncthreads();
        sm[t] += x;
        __syncthreads();
    }
    if (i < n) localex[i] = sm[t] - v;
    if (t == 255) bsum[blockIdx.x] = sm[255];
}

__global__ __launch_bounds__(256) void scan_bsum(int* __restrict__ bsum, int nb) {
    __shared__ int sm[256];
    __shared__ int carry;
    int t = threadIdx.x;
    if (t == 0) carry = 0;
    __syncthreads();
    for (int base = 0; base < nb; base += 256) {
        int i = base + t;
        int v = (i < nb) ? bsum[i] : 0;
        sm[t] = v;
        __syncthreads();
        for (int d = 1; d < 256; d <<= 1) {
            int x = (t >= d) ? sm[t - d] : 0;
            __syncthreads();
            sm[t] += x;
            __syncthreads();
        }
        int excl = sm[t] - v + carry;
        if (i < nb) bsum[i] = excl;
        __syncthreads();
        if (t == 255) carry += sm[255];
        __syncthreads();
    }
}

__global__ void scan_add(int* __restrict__ localex, const int* __restrict__ bsum, int n,
                         int* __restrict__ cursor) {
    int i = blockIdx.x * 256 + threadIdx.x;
    if (i < n) {
        int v = localex[i] + bsum[blockIdx.x];
        localex[i] = v;
        cursor[i] = v;
    }
}

__global__ void scatter_all(SrcTab st, int* __restrict__ cursor,
                            int2* __restrict__ epair, int total) {
    int i = blockIdx.x * 256 + threadIdx.x;
    if (i >= total) return;
    int s = 0;
    while (i >= st.pre[s + 1]) ++s;
    int j = i - st.pre[s];
    int key = st.kbase[s] + st.rows[s][j] * st.mulS[s] + st.slot[s];
    int p = atomicAdd(&cursor[key], 1);
    epair[p] = make_int2(st.cols[s][j] + st.tbase[s], __float_as_int(st.vals[s][j]));
}

// ---------------------------------------------------------------------------
// fused per-level SPMM: acc[row] = sum over ALL sources of this level
// (contiguous CSR range [rstart[Kb+row*S], rstart[Kb+(row+1)*S]) ), bf16 out.
// one wave per row, 4 cols/lane, inner loop pipelined x4.
// ---------------------------------------------------------------------------
__global__ __launch_bounds__(256) void spmm_level(const int2* __restrict__ epair,
                                                  const int* __restrict__ rstart,
                                                  const __bf16* __restrict__ T,
                                                  __bf16* __restrict__ acc,
                                                  int Kb, int S, int nrows) {
    int row = blockIdx.x * 4 + (threadIdx.x >> 6);
    if (row >= nrows) return;
    int l = threadIdx.x & 63;
    int s = rstart[Kb + row * S];
    int e = rstart[Kb + row * S + S];
    const unsigned short* Tb = (const unsigned short*)T + l * 4;
    float4 a0 = make_float4(0.f, 0.f, 0.f, 0.f);
    for (int base = s; base < e; base += 64) {
        int j = base + l;
        int off = 0; float v = 0.f;
        if (j < e) { int2 ee = epair[j]; off = ee.x; v = __int_as_float(ee.y); }
        int lim = e - base; if (lim > 64) lim = 64;
        int i = 0;
        for (; i + 4 <= lim; i += 4) {
            int   ob0 = __shfl(off, i,     64), ob1 = __shfl(off, i + 1, 64);
            int   ob2 = __shfl(off, i + 2, 64), ob3 = __shfl(off, i + 3, 64);
            float vb0 = __shfl(v,   i,     64), vb1 = __shfl(v,   i + 1, 64);
            float vb2 = __shfl(v,   i + 2, 64), vb3 = __shfl(v,   i + 3, 64);
            uint2 u0 = *(const uint2*)(Tb + (size_t)ob0 * CC);
            uint2 u1 = *(const uint2*)(Tb + (size_t)ob1 * CC);
            uint2 u2 = *(const uint2*)(Tb + (size_t)ob2 * CC);
            uint2 u3 = *(const uint2*)(Tb + (size_t)ob3 * CC);
            a0.x += vb0 * __uint_as_float(u0.x << 16);
            a0.y += vb0 * __uint_as_float(u0.x & 0xFFFF0000u);
            a0.z += vb0 * __uint_as_float(u0.y << 16);
            a0.w += vb0 * __uint_as_float(u0.y & 0xFFFF0000u);
            a0.x += vb1 * __uint_as_float(u1.x << 16);
            a0.y += vb1 * __uint_as_float(u1.x & 0xFFFF0000u);
            a0.z += vb1 * __uint_as_float(u1.y << 16);
            a0.w += vb1 * __uint_as_float(u1.y & 0xFFFF0000u);
            a0.x += vb2 * __uint_as_float(u2.x << 16);
            a0.y += vb2 * __uint_as_float(u2.x & 0xFFFF0000u);
            a0.z += vb2 * __uint_as_float(u2.y << 16);
            a0.w += vb2 * __uint_as_float(u2.y & 0xFFFF0000u);
            a0.x += vb3 * __uint_as_float(u3.x << 16);
            a0.y += vb3 * __uint_as_float(u3.x & 0xFFFF0000u);
            a0.z += vb3 * __uint_as_float(u3.y << 16);
            a0.w += vb3 * __uint_as_float(u3.y & 0xFFFF0000u);
        }
        for (; i < lim; ++i) {
            int   ob = __shfl(off, i, 64);
            float vb = __shfl(v, i, 64);
            uint2 u = *(const uint2*)(Tb + (size_t)ob * CC);
            a0.x += vb * __uint_as_float(u.x << 16);
            a0.y += vb * __uint_as_float(u.x & 0xFFFF0000u);
            a0.z += vb * __uint_as_float(u.y << 16);
            a0.w += vb * __uint_as_float(u.y & 0xFFFF0000u);
        }
    }
    bf16x4 o;
    o[0] = (__bf16)a0.x; o[1] = (__bf16)a0.y; o[2] = (__bf16)a0.z; o[3] = (__bf16)a0.w;
    *(bf16x4*)(acc + (size_t)row * CC + l * 4) = o;
}

// ---------------------------------------------------------------------------
__global__ void seg_count_all(const int* __restrict__ s0, const int* __restrict__ s1,
                              const int* __restrict__ s2, int* __restrict__ cnt) {
    int i = blockIdx.x * 256 + threadIdx.x;
    int a = (i < NN0) ? s0[i] : -1;
    int b = (i < NN1) ? s1[i] : -1;
    int c = (i < NN2) ? s2[i] : -1;
#pragma unroll
    for (int v = 0; v < BB; ++v) {
        unsigned long long m0 = __ballot(a == v);
        unsigned long long m1 = __ballot(b == v);
        unsigned long long m2 = __ballot(c == v);
        if ((threadIdx.x & 63) == 0) {
            if (m0) atomicAdd(&cnt[v], (int)__popcll(m0));
            if (m1) atomicAdd(&cnt[8 + v], (int)__popcll(m1));
            if (m2) atomicAdd(&cnt[16 + v], (int)__popcll(m2));
        }
    }
}

// ---------------------------------------------------------------------------
// poolh[seg] += sigmoid(acc_bf16[node]) — sorted-seg run-length accumulate
// ---------------------------------------------------------------------------
__global__ __launch_bounds__(256) void pool_sigmoid(const __bf16* __restrict__ acc,
                                                    const int* __restrict__ seg,
                                                    float* __restrict__ poolh, int n) {
    const unsigned short* A = (const unsigned short*)acc;
    int c = threadIdx.x;
    int node0 = blockIdx.x * 64;
    int nend = min(node0 + 64, n);
    float run = 0.f;
    int curseg = seg[node0];
    for (int node = node0; node < nend; ++node) {
        int s = seg[node];
        float a = __uint_as_float((unsigned)A[(size_t)node * CC + c] << 16);
        float h = 1.f / (1.f + __expf(-a));
        if (s != curseg) {
            atomicAdd(&poolh[curseg * CC + c], run);
            run = 0.f; curseg = s;
        }
        run += h;
    }
    atomicAdd(&poolh[curseg * CC + c], run);
}

__global__ __launch_bounds__(64) void final_head(const float* __restrict__ ph0,
                                                 const float* __restrict__ ph1,
                                                 const float* __restrict__ ph2,
                                                 const int* __restrict__ c0,
                                                 const int* __restrict__ c1,
                                                 const int* __restrict__ c2,
                                                 const float* __restrict__ W0,
                                                 const float* __restrict__ W1,
                                                 const float* __restrict__ W2,
                                                 const float* __restrict__ b0,
                                                 const float* __restrict__ b1,
                                                 const float* __restrict__ b2,
                                                 float* __restrict__ out) {
    int s = blockIdx.x, o = threadIdx.x;
    float inv0 = 1.f / fmaxf((float)c0[s], 1.f);
    float inv1 = 1.f / fmaxf((float)c1[s], 1.f);
    float inv2 = 1.f / fmaxf((float)c2[s], 1.f);
    float a0 = 0.f, a1 = 0.f, a2 = 0.f;
    for (int k = 0; k < CC; ++k) {
        a0 += ph0[s * CC + k] * W0[k * OUTD + o];
        a1 += ph1[s * CC + k] * W1[k * OUTD + o];
        a2 += ph2[s * CC + k] * W2[k * OUTD + o];
    }
    out[s * OUTD + o] = (a0 * inv0 + b0[o] + a1 * inv1 + b1[o] + a2 * inv2 + b2[o]) * (1.f / 3.f);
}

// ---------------------------------------------------------------------------
extern "C" void kernel_launch(void* const* d_in, const int* in_sizes, int n_in,
                              void* d_out, int out_size, void* d_ws, size_t ws_size,
                              hipStream_t stream) {
    const float* x0 = (const float*)d_in[0];
    const float* x1 = (const float*)d_in[1];
    const float* x2 = (const float*)d_in[2];
    const int* belong0 = (const int*)d_in[27];
    const int* belong1 = (const int*)d_in[28];
    const int* belong2 = (const int*)d_in[29];

    // ---- workspace layout (bytes), ~107 MB total ----
    char* w = (char*)d_ws;
    __bf16* T    = (__bf16*)w;  w += (size_t)120000 * CC * 2;  // 61.44 MB (max level rows)
    __bf16* accb = (__bf16*)w;  w += (size_t)NN1 * CC * 2;     // 30.72 MB
    __bf16* Wt   = (__bf16*)w;  w += (size_t)7 * CC * CC * 2;
    int2*   epair= (int2*)w;    w += (size_t)ECAP * 8;
    int*    cnt  = (int*)w;     w += (size_t)CTOT * 4;         // zero-region start
    float*  poolh= (float*)w;   w += 3 * BB * CC * 4;
    int*    segc = (int*)w;     w += 32 * 4;                   // zero-region end
    int*    rstart=(int*)w;     w += (size_t)CTOT * 4;
    int*    cursor=(int*)w;     w += (size_t)CTOT * 4;
    int*    bsum = (int*)w;     w += 2048 * 4;
    int* cnt0 = segc, *cnt1 = segc + 8, *cnt2 = segc + 16;

    // ---- source table: order adj0, inc1 | inc1t, adjd1, adju1, inc2 | inc2t, adjd2
    const int bases[8] = {15, 3, 9, 21, 18, 6, 12, 24};
    const int kbase[8] = {KB_L0, KB_L0, KB_L1, KB_L1, KB_L1, KB_L1, KB_L2, KB_L2};
    const int mulS [8] = {2, 2, 3, 3, 3, 3, 2, 2};
    const int slot [8] = {0, 1, 0, 1, 1, 2, 0, 1};
    const int tbase[8] = {0, 20000, 0, 20000, 20000, 80000, 0, 60000};
    SrcTab st;
    int run = 0;
    for (int s = 0; s < 8; ++s) {
        st.rows[s] = (const int*)d_in[bases[s]];
        st.cols[s] = (const int*)d_in[bases[s] + 1];
        st.vals[s] = (const float*)d_in[bases[s] + 2];
        st.kbase[s] = kbase[s]; st.mulS[s] = mulS[s];
        st.slot[s] = slot[s];   st.tbase[s] = tbase[s];
        st.pre[s] = run;
        run += in_sizes[bases[s]];
    }
    st.pre[8] = run;
    const int total = run;

    WTab wt;
    for (int i = 0; i < 7; ++i) wt.w[i] = (const float*)d_in[30 + i];

    // ---- CSR build (level-fused keys) + weight convert + seg counts ----
    zero_kernel<<<512, 256, 0, stream>>>((float4*)cnt, (CTOT * 4 + 3 * BB * CC * 4 + 128) / 16);
    hist_all<<<(total + 255) / 256, 256, 0, stream>>>(st, cnt, total);
    convert_w<<<7 * 256, 256, 0, stream>>>(wt, Wt);
    seg_count_all<<<(NN1 + 255) / 256, 256, 0, stream>>>(belong0, belong1, belong2, segc);
    scan_blocks<<<NBLK, 256, 0, stream>>>(cnt, CTOT, rstart, bsum);
    scan_bsum<<<1, 256, 0, stream>>>(bsum, NBLK);
    scan_add<<<NBLK, 256, 0, stream>>>(rstart, bsum, CTOT, cursor);
    scatter_all<<<(total + 255) / 256, 256, 0, stream>>>(st, cursor, epair, total);

    // ---- level 0: T = [x0@W00 (20k) | x1@W10 (60k)] ----
    {
        GemmTab g; g.j[0] = {x0, 0, 0, NN0}; g.j[1] = {x1, 1, 20000, NN1};
        gemm_level<<<dim3((NN1 + 127) / 128, 2, 2), 256, 0, stream>>>(g, Wt, T);
        spmm_level<<<(NN0 + 3) / 4, 256, 0, stream>>>(epair, rstart, T, accb, KB_L0, 2, NN0);
        pool_sigmoid<<<(NN0 + 63) / 64, 256, 0, stream>>>(accb, belong0, poolh, NN0);
    }
    // ---- level 1: T = [x0@W01 (20k) | x1@W11 (60k) | x2@W21 (40k)] ----
    {
        GemmTab g; g.j[0] = {x0, 2, 0, NN0}; g.j[1] = {x1, 3, 20000, NN1};
        g.j[2] = {x2, 4, 80000, NN2};
        gemm_level<<<dim3((NN1 + 127) / 128, 2, 3), 256, 0, stream>>>(g, Wt, T);
        spmm_level<<<(NN1 + 3) / 4, 256, 0, stream>>>(epair, rstart, T, accb, KB_L1, 3, NN1);
        pool_sigmoid<<<(NN1 + 63) / 64, 256, 0, stream>>>(accb, belong1, poolh + BB * CC, NN1);
    }
    // ---- level 2: T = [x1@W12 (60k) | x2@W22 (40k)] ----
    {
        GemmTab g; g.j[0] = {x1, 5, 0, NN1}; g.j[1] = {x2, 6, 60000, NN2};
        gemm_level<<<dim3((NN1 + 127) / 128, 2, 2), 256, 0, stream>>>(g, Wt, T);
        spmm_level<<<(NN2 + 3) / 4, 256, 0, stream>>>(epair, rstart, T, accb, KB_L2, 2, NN2);
        pool_sigmoid<<<(NN2 + 63) / 64, 256, 0, stream>>>(accb, belong2, poolh + 2 * BB * CC, NN2);
    }

    // ---- combine ----
    final_head<<<BB, 64, 0, stream>>>(poolh, poolh + BB * CC, poolh + 2 * BB * CC,
                                      cnt0, cnt1, cnt2,
                                      (const float*)d_in[37], (const float*)d_in[38],
                                      (const float*)d_in[39], (const float*)d_in[40],
                                      (const float*)d_in[41], (const float*)d_in[42],
                                      (float*)d_out);
}

// Round 8
// 686.855 us; speedup vs baseline: 10.4957x; 1.0616x over previous
//
#include <hip/hip_runtime.h>
#include <math.h>

#define NN0 20000
#define NN1 60000
#define NN2 40000
#define CC 256
#define OUTD 64
#define BB 8

// key space: L0 = row*2+slot in [0,40000); L1 = 40000+row*3+slot; L2 = 220000+row*2+slot
#define KB_L0 0
#define KB_L1 40000
#define KB_L2 220000
#define CTOT  300288      // 1173 * 256 (padded; pad counters stay 0)
#define NBLK  1173
#define ECAP  1300000

// X tiling (128-row tiles): x0 157, x1 469, x2 313 -> 939 tiles
#define XT0 0
#define XT1 157
#define XT2 626
#define XTTOT 939

typedef __bf16 bf16x8 __attribute__((ext_vector_type(8)));
typedef __bf16 bf16x4 __attribute__((ext_vector_type(4)));
typedef float  f32x4  __attribute__((ext_vector_type(4)));

__device__ __forceinline__ void glds16(const __bf16* g, __bf16* l) {
    __builtin_amdgcn_global_load_lds(
        (const __attribute__((address_space(1))) void*)g,
        (__attribute__((address_space(3))) void*)l, 16, 0, 0);
}

// ---------------------------------------------------------------------------
__global__ void zero_kernel(float4* __restrict__ p, long n4) {
    long i = (long)blockIdx.x * blockDim.x + threadIdx.x;
    long stride = (long)gridDim.x * blockDim.x;
    for (; i < n4; i += stride) p[i] = make_float4(0.f, 0.f, 0.f, 0.f);
}

// ---------------------------------------------------------------------------
struct WTab { const float* w[7]; };

// old-path: W (k-major fp32) -> Wt (n-major bf16)
__global__ void convert_w_old(WTab wt, __bf16* __restrict__ Wt) {
    int b = blockIdx.x;            // 7*256
    int w = b >> 8, n = b & 255;
    int k = threadIdx.x;
    Wt[((size_t)w * 256 + n) * 256 + k] = (__bf16)wt.w[w][k * 256 + n];
}

// new-path: W -> staging-tiled [(w*2+cb)*32+g][n] 16B granules
__global__ __launch_bounds__(256) void convert_w_tiled(WTab wt, __bf16* __restrict__ WtT) {
    int idx = blockIdx.x * 256 + threadIdx.x;   // 57344 slots
    int w = idx >> 13;
    int rem = idx & 8191;
    int cb = rem >> 12;
    int rem2 = rem & 4095;
    int g = rem2 >> 7, n = rem2 & 127;
    const float* W = wt.w[w];
    int col = cb * 128 + n;
    bf16x8 pk;
#pragma unroll
    for (int j = 0; j < 8; ++j) pk[j] = (__bf16)W[(g * 8 + j) * CC + col];
    *(bf16x8*)(WtT + (size_t)idx * 8) = pk;
}

// new-path: X fp32 -> staging-tiled bf16 [tile][g][m], zero-padded tail rows
struct XcvtTab { const float* src[3]; int tstart[4]; int nrows[3]; };
__global__ __launch_bounds__(256) void convert_x_tiled(XcvtTab xt, __bf16* __restrict__ XbT) {
    int tile = blockIdx.x;
    int s = (tile >= xt.tstart[1] ? 1 : 0) + (tile >= xt.tstart[2] ? 1 : 0);
    const float* src = xt.src[s];
    int row0 = (tile - xt.tstart[s]) * 128;
    int nrows = xt.nrows[s];
    __bf16* dst = XbT + (size_t)tile * 4096 * 8;
    for (int slot = threadIdx.x; slot < 4096; slot += 256) {
        int g = slot >> 7, m = slot & 127;
        int r = row0 + m;
        bf16x8 pk;
        if (r < nrows) {
            const float* p = src + (size_t)r * CC + g * 8;
            float4 f0 = *(const float4*)p;
            float4 f1 = *(const float4*)(p + 4);
            pk[0] = (__bf16)f0.x; pk[1] = (__bf16)f0.y; pk[2] = (__bf16)f0.z; pk[3] = (__bf16)f0.w;
            pk[4] = (__bf16)f1.x; pk[5] = (__bf16)f1.y; pk[6] = (__bf16)f1.z; pk[7] = (__bf16)f1.w;
        } else {
#pragma unroll
            for (int j = 0; j < 8; ++j) pk[j] = (__bf16)0.f;
        }
        *(bf16x8*)(dst + (size_t)slot * 8) = pk;
    }
}

// ---------------------------------------------------------------------------
struct GemmJob { const float* X; int xTile; int wIdx; int rowBase; int M; };
struct GemmTab { GemmJob j[3]; };

// new-path GEMM: bf16 tiled inputs, global_load_lds staging (m97 structure)
__global__ __launch_bounds__(256) void gemm_glds(GemmTab tab,
                                                 const __bf16* __restrict__ WtT,
                                                 const __bf16* __restrict__ XbT,
                                                 __bf16* __restrict__ T) {
    const GemmJob job = tab.j[blockIdx.z];
    const int row0 = blockIdx.x * 128;
    if (row0 >= job.M) return;
    const int M = job.M;

    __shared__ __bf16 Als[4096];
    __shared__ __bf16 Bls[4096];
    const int t = threadIdx.x;
    const int col0 = blockIdx.y * 128;
    const int lane = t & 63, wave = t >> 6;
    const int q = lane >> 4, lm = lane & 15;
    const int wm = (wave & 1) * 64, wn = (wave >> 1) * 64;

    f32x4 acc[4][4];
    const f32x4 z = {0.f, 0.f, 0.f, 0.f};
#pragma unroll
    for (int i = 0; i < 4; ++i)
#pragma unroll
        for (int j = 0; j < 4; ++j) acc[i][j] = z;

    // staging: per wave two issues, slots sb = wave*128 + s*64 (slot = g*128+m)
    const int sb0 = wave * 128, sb1 = sb0 + 64;
    const int g0 = sb0 >> 7, m0 = (sb0 & 127) + lane;
    const int g1 = sb1 >> 7, m1 = (sb1 & 127) + lane;
    const __bf16* aSrc0 = XbT + (((size_t)(job.xTile + blockIdx.x) * 32 + g0) * 128 + m0) * 8;
    const __bf16* aSrc1 = XbT + (((size_t)(job.xTile + blockIdx.x) * 32 + g1) * 128 + m1) * 8;
    const __bf16* bSrc0 = WtT + (((size_t)(job.wIdx * 2 + blockIdx.y) * 32 + g0) * 128 + m0) * 8;
    const __bf16* bSrc1 = WtT + (((size_t)(job.wIdx * 2 + blockIdx.y) * 32 + g1) * 128 + m1) * 8;
    __bf16* aDst0 = &Als[(sb0 + lane) * 8];
    __bf16* aDst1 = &Als[(sb1 + lane) * 8];
    __bf16* bDst0 = &Bls[(sb0 + lane) * 8];
    __bf16* bDst1 = &Bls[(sb1 + lane) * 8];

    for (int it = 0; it < 8; ++it) {
        glds16(aSrc0, aDst0); glds16(aSrc1, aDst1);
        glds16(bSrc0, bDst0); glds16(bSrc1, bDst1);
        aSrc0 += 4096; aSrc1 += 4096; bSrc0 += 4096; bSrc1 += 4096;
        __syncthreads();
        bf16x8 af[4], bfr[4];
#pragma unroll
        for (int i = 0; i < 4; ++i)
            af[i] = *(bf16x8*)&Als[(q * 128 + wm + 16 * i + lm) * 8];
#pragma unroll
        for (int j = 0; j < 4; ++j)
            bfr[j] = *(bf16x8*)&Bls[(q * 128 + wn + 16 * j + lm) * 8];
#pragma unroll
        for (int i = 0; i < 4; ++i)
#pragma unroll
            for (int j = 0; j < 4; ++j)
                acc[i][j] = __builtin_amdgcn_mfma_f32_16x16x32_bf16(af[i], bfr[j], acc[i][j], 0, 0, 0);
        __syncthreads();
    }
#pragma unroll
    for (int i = 0; i < 4; ++i) {
        int gr0 = row0 + wm + 16 * i + q * 4;
#pragma unroll
        for (int r = 0; r < 4; ++r) {
            int grow = gr0 + r;
            if (grow < M) {
                __bf16* dst = T + (size_t)(job.rowBase + grow) * CC + col0 + wn + lm;
#pragma unroll
                for (int j = 0; j < 4; ++j) dst[16 * j] = (__bf16)acc[i][j][r];
            }
        }
    }
}

// old-path GEMM (round-7): fp32 X staging with on-the-fly pack
__global__ __launch_bounds__(256) void gemm_level(GemmTab tab,
                                                  const __bf16* __restrict__ WtAll,
                                                  __bf16* __restrict__ T) {
    const GemmJob job = tab.j[blockIdx.z];
    const int row0 = blockIdx.x * 128;
    if (row0 >= job.M) return;
    const int M = job.M;
    const float* __restrict__ X = job.X;
    const __bf16* __restrict__ Wt = WtAll + (size_t)job.wIdx * CC * CC;

    __shared__ __bf16 Als[4096];
    __shared__ __bf16 Bls[4096];
    const int t = threadIdx.x;
    const int col0 = blockIdx.y * 128;
    const int lane = t & 63, wave = t >> 6;
    const int q = lane >> 4, lm = lane & 15;
    const int wm = (wave & 1) * 64, wn = (wave >> 1) * 64;

    f32x4 acc[4][4];
    const f32x4 z = {0.f, 0.f, 0.f, 0.f};
#pragma unroll
    for (int i = 0; i < 4; ++i)
#pragma unroll
        for (int j = 0; j < 4; ++j) acc[i][j] = z;

    const int g0 = t >> 7, ms = t & 127;
    int arow = row0 + ms; if (arow > M - 1) arow = M - 1;
    const float*  ap = X  + (size_t)arow * CC;
    const __bf16* bp = Wt + (size_t)(col0 + ms) * CC;

    for (int kk = 0; kk < CC; kk += 32) {
#pragma unroll
        for (int s = 0; s < 2; ++s) {
            int g = g0 + s * 2;
            float4 f0 = *(const float4*)(ap + kk + g * 8);
            float4 f1 = *(const float4*)(ap + kk + g * 8 + 4);
            bf16x8 pk;
            pk[0] = (__bf16)f0.x; pk[1] = (__bf16)f0.y; pk[2] = (__bf16)f0.z; pk[3] = (__bf16)f0.w;
            pk[4] = (__bf16)f1.x; pk[5] = (__bf16)f1.y; pk[6] = (__bf16)f1.z; pk[7] = (__bf16)f1.w;
            *(bf16x8*)&Als[(g * 128 + ms) * 8] = pk;
            *(bf16x8*)&Bls[(g * 128 + ms) * 8] = *(const bf16x8*)(bp + kk + g * 8);
        }
        __syncthreads();
        bf16x8 af[4], bfr[4];
#pragma unroll
        for (int i = 0; i < 4; ++i)
            af[i] = *(bf16x8*)&Als[(q * 128 + wm + 16 * i + lm) * 8];
#pragma unroll
        for (int j = 0; j < 4; ++j)
            bfr[j] = *(bf16x8*)&Bls[(q * 128 + wn + 16 * j + lm) * 8];
#pragma unroll
        for (int i = 0; i < 4; ++i)
#pragma unroll
            for (int j = 0; j < 4; ++j)
                acc[i][j] = __builtin_amdgcn_mfma_f32_16x16x32_bf16(af[i], bfr[j], acc[i][j], 0, 0, 0);
        __syncthreads();
    }
#pragma unroll
    for (int i = 0; i < 4; ++i) {
        int gr0 = row0 + wm + 16 * i + q * 4;
#pragma unroll
        for (int r = 0; r < 4; ++r) {
            int grow = gr0 + r;
            if (grow < M) {
                __bf16* dst = T + (size_t)(job.rowBase + grow) * CC + col0 + wn + lm;
#pragma unroll
                for (int j = 0; j < 4; ++j) dst[16 * j] = (__bf16)acc[i][j][r];
            }
        }
    }
}

// ---------------------------------------------------------------------------
// batched CSR build over 8 COO sources, level-fused keys
// ---------------------------------------------------------------------------
struct SrcTab {
    const int*   rows[8];
    const int*   cols[8];
    const float* vals[8];
    int pre[9];
    int kbase[8];
    int mulS[8];
    int slot[8];
    int tbase[8];
};

__global__ void hist_all(SrcTab st, int* __restrict__ cnt, int total) {
    int i = blockIdx.x * 256 + threadIdx.x;
    if (i >= total) return;
    int s = 0;
    while (i >= st.pre[s + 1]) ++s;
    int j = i - st.pre[s];
    int key = st.kbase[s] + st.rows[s][j] * st.mulS[s] + st.slot[s];
    atomicAdd(&cnt[key], 1);
}

__global__ __launch_bounds__(256) void scan_blocks(const int* __restrict__ cnt, int n,
                                                   int* __restrict__ localex,
                                                   int* __restrict__ bsum) {
    __shared__ int sm[256];
    int t = threadIdx.x;
    int i = blockIdx.x * 256 + t;
    int v = (i < n) ? cnt[i] : 0;
    sm[t] = v;
    __syncthreads();
    for (int d = 1; d < 256; d <<= 1) {
        int x = (t >= d) ? sm[t - d] : 0;
        __syncthreads();
        sm[t] += x;
        __syncthreads();
    }
    if (i < n) localex[i] = sm[t] - v;
    if (t == 255) bsum[blockIdx.x] = sm[255];
}

__global__ __launch_bounds__(256) void scan_bsum(int* __restrict__ bsum, int nb) {
    __shared__ int sm[256];
    __shared__ int carry;
    int t = threadIdx.x;
    if (t == 0) carry = 0;
    __syncthreads();
    for (int base = 0; base < nb; base += 256) {
        int i = base + t;
        int v = (i < nb) ? bsum[i] : 0;
        sm[t] = v;
        __syncthreads();
        for (int d = 1; d < 256; d <<= 1) {
            int x = (t >= d) ? sm[t - d] : 0;
            __syncthreads();
            sm[t] += x;
            __syncthreads();
        }
        int excl = sm[t] - v + carry;
        if (i < nb) bsum[i] = excl;
        __syncthreads();
        if (t == 255) carry += sm[255];
        __syncthreads();
    }
}

__global__ void scan_add(int* __restrict__ localex, const int* __restrict__ bsum, int n,
                         int* __restrict__ cursor) {
    int i = blockIdx.x * 256 + threadIdx.x;
    if (i < n) {
        int v = localex[i] + bsum[blockIdx.x];
        localex[i] = v;
        cursor[i] = v;
    }
}

// 2 entries/thread: two independent atomic->store chains in flight
__global__ void scatter_all(SrcTab st, int* __restrict__ cursor,
                            int2* __restrict__ epair, int total, int half) {
    int i0 = blockIdx.x * 256 + threadIdx.x;
    int i1 = i0 + half;
    bool v0 = i0 < half, v1 = i1 < total;
    int key0 = 0, key1 = 0;
    int2 e0, e1;
    if (v0) {
        int s = 0;
        while (i0 >= st.pre[s + 1]) ++s;
        int j = i0 - st.pre[s];
        key0 = st.kbase[s] + st.rows[s][j] * st.mulS[s] + st.slot[s];
        e0 = make_int2(st.cols[s][j] + st.tbase[s], __float_as_int(st.vals[s][j]));
    }
    if (v1) {
        int s = 0;
        while (i1 >= st.pre[s + 1]) ++s;
        int j = i1 - st.pre[s];
        key1 = st.kbase[s] + st.rows[s][j] * st.mulS[s] + st.slot[s];
        e1 = make_int2(st.cols[s][j] + st.tbase[s], __float_as_int(st.vals[s][j]));
    }
    int p0 = v0 ? atomicAdd(&cursor[key0], 1) : 0;
    int p1 = v1 ? atomicAdd(&cursor[key1], 1) : 0;
    if (v0) epair[p0] = e0;
    if (v1) epair[p1] = e1;
}

// ---------------------------------------------------------------------------
// fused per-level SPMM, gather pipelined x8/x4/x1
// ---------------------------------------------------------------------------
__global__ __launch_bounds__(256) void spmm_level(const int2* __restrict__ epair,
                                                  const int* __restrict__ rstart,
                                                  const __bf16* __restrict__ T,
                                                  __bf16* __restrict__ acc,
                                                  int Kb, int S, int nrows) {
    int row = blockIdx.x * 4 + (threadIdx.x >> 6);
    if (row >= nrows) return;
    int l = threadIdx.x & 63;
    int s0 = rstart[Kb + row * S];
    int e = rstart[Kb + row * S + S];
    const unsigned short* Tb = (const unsigned short*)T + l * 4;
    float4 a0 = make_float4(0.f, 0.f, 0.f, 0.f);
    for (int base = s0; base < e; base += 64) {
        int j = base + l;
        int off = 0; float v = 0.f;
        if (j < e) { int2 ee = epair[j]; off = ee.x; v = __int_as_float(ee.y); }
        int lim = e - base; if (lim > 64) lim = 64;
        int i = 0;
        for (; i + 8 <= lim; i += 8) {
            int ob[8]; float vb[8]; uint2 u[8];
#pragma unroll
            for (int p = 0; p < 8; ++p) { ob[p] = __shfl(off, i + p, 64); vb[p] = __shfl(v, i + p, 64); }
#pragma unroll
            for (int p = 0; p < 8; ++p) u[p] = *(const uint2*)(Tb + (size_t)ob[p] * CC);
#pragma unroll
            for (int p = 0; p < 8; ++p) {
                a0.x += vb[p] * __uint_as_float(u[p].x << 16);
                a0.y += vb[p] * __uint_as_float(u[p].x & 0xFFFF0000u);
                a0.z += vb[p] * __uint_as_float(u[p].y << 16);
                a0.w += vb[p] * __uint_as_float(u[p].y & 0xFFFF0000u);
            }
        }
        for (; i + 4 <= lim; i += 4) {
            int ob[4]; float vb[4]; uint2 u[4];
#pragma unroll
            for (int p = 0; p < 4; ++p) { ob[p] = __shfl(off, i + p, 64); vb[p] = __shfl(v, i + p, 64); }
#pragma unroll
            for (int p = 0; p < 4; ++p) u[p] = *(const uint2*)(Tb + (size_t)ob[p] * CC);
#pragma unroll
            for (int p = 0; p < 4; ++p) {
                a0.x += vb[p] * __uint_as_float(u[p].x << 16);
                a0.y += vb[p] * __uint_as_float(u[p].x & 0xFFFF0000u);
                a0.z += vb[p] * __uint_as_float(u[p].y << 16);
                a0.w += vb[p] * __uint_as_float(u[p].y & 0xFFFF0000u);
            }
        }
        for (; i < lim; ++i) {
            int   ob = __shfl(off, i, 64);
            float vb = __shfl(v, i, 64);
            uint2 u = *(const uint2*)(Tb + (size_t)ob * CC);
            a0.x += vb * __uint_as_float(u.x << 16);
            a0.y += vb * __uint_as_float(u.x & 0xFFFF0000u);
            a0.z += vb * __uint_as_float(u.y << 16);
            a0.w += vb * __uint_as_float(u.y & 0xFFFF0000u);
        }
    }
    bf16x4 o;
    o[0] = (__bf16)a0.x; o[1] = (__bf16)a0.y; o[2] = (__bf16)a0.z; o[3] = (__bf16)a0.w;
    *(bf16x4*)(acc + (size_t)row * CC + l * 4) = o;
}

// ---------------------------------------------------------------------------
__global__ void seg_count_all(const int* __restrict__ s0, const int* __restrict__ s1,
                              const int* __restrict__ s2, int* __restrict__ cnt) {
    int i = blockIdx.x * 256 + threadIdx.x;
    int a = (i < NN0) ? s0[i] : -1;
    int b = (i < NN1) ? s1[i] : -1;
    int c = (i < NN2) ? s2[i] : -1;
#pragma unroll
    for (int v = 0; v < BB; ++v) {
        unsigned long long m0 = __ballot(a == v);
        unsigned long long m1 = __ballot(b == v);
        unsigned long long m2 = __ballot(c == v);
        if ((threadIdx.x & 63) == 0) {
            if (m0) atomicAdd(&cnt[v], (int)__popcll(m0));
            if (m1) atomicAdd(&cnt[8 + v], (int)__popcll(m1));
            if (m2) atomicAdd(&cnt[16 + v], (int)__popcll(m2));
        }
    }
}

__global__ __launch_bounds__(256) void pool_sigmoid(const __bf16* __restrict__ acc,
                                                    const int* __restrict__ seg,
                                                    float* __restrict__ poolh, int n) {
    const unsigned short* A = (const unsigned short*)acc;
    int c = threadIdx.x;
    int node0 = blockIdx.x * 64;
    int nend = min(node0 + 64, n);
    float run = 0.f;
    int curseg = seg[node0];
    for (int node = node0; node < nend; ++node) {
        int s = seg[node];
        float a = __uint_as_float((unsigned)A[(size_t)node * CC + c] << 16);
        float h = 1.f / (1.f + __expf(-a));
        if (s != curseg) {
            atomicAdd(&poolh[curseg * CC + c], run);
            run = 0.f; curseg = s;
        }
        run += h;
    }
    atomicAdd(&poolh[curseg * CC + c], run);
}

__global__ __launch_bounds__(64) void final_head(const float* __restrict__ ph0,
                                                 const float* __restrict__ ph1,
                                                 const float* __restrict__ ph2,
                                                 const int* __restrict__ c0,
                                                 const int* __restrict__ c1,
                                                 const int* __restrict__ c2,
                                                 const float* __restrict__ W0,
                                                 const float* __restrict__ W1,
                                                 const float* __restrict__ W2,
                                                 const float* __restrict__ b0,
                                                 const float* __restrict__ b1,
                                                 const float* __restrict__ b2,
                                                 float* __restrict__ out) {
    int s = blockIdx.x, o = threadIdx.x;
    float inv0 = 1.f / fmaxf((float)c0[s], 1.f);
    float inv1 = 1.f / fmaxf((float)c1[s], 1.f);
    float inv2 = 1.f / fmaxf((float)c2[s], 1.f);
    float a0 = 0.f, a1 = 0.f, a2 = 0.f;
    for (int k = 0; k < CC; ++k) {
        a0 += ph0[s * CC + k] * W0[k * OUTD + o];
        a1 += ph1[s * CC + k] * W1[k * OUTD + o];
        a2 += ph2[s * CC + k] * W2[k * OUTD + o];
    }
    out[s * OUTD + o] = (a0 * inv0 + b0[o] + a1 * inv1 + b1[o] + a2 * inv2 + b2[o]) * (1.f / 3.f);
}

// ---------------------------------------------------------------------------
extern "C" void kernel_launch(void* const* d_in, const int* in_sizes, int n_in,
                              void* d_out, int out_size, void* d_ws, size_t ws_size,
                              hipStream_t stream) {
    const float* x0 = (const float*)d_in[0];
    const float* x1 = (const float*)d_in[1];
    const float* x2 = (const float*)d_in[2];
    const int* belong0 = (const int*)d_in[27];
    const int* belong1 = (const int*)d_in[28];
    const int* belong2 = (const int*)d_in[29];

    // ---- workspace layout (bytes) ----
    char* w = (char*)d_ws;
    __bf16* T    = (__bf16*)w;  w += (size_t)120000 * CC * 2;  // 61.44 MB
    __bf16* accb = (__bf16*)w;  w += (size_t)NN1 * CC * 2;     // 30.72 MB
    __bf16* Wt   = (__bf16*)w;  w += (size_t)7 * CC * CC * 2;  // both layouts fit
    int2*   epair= (int2*)w;    w += (size_t)ECAP * 8;
    int*    cnt  = (int*)w;     w += (size_t)CTOT * 4;         // zero-region start
    float*  poolh= (float*)w;   w += 3 * BB * CC * 4;
    int*    segc = (int*)w;     w += 32 * 4;                   // zero-region end
    int*    rstart=(int*)w;     w += (size_t)CTOT * 4;
    int*    cursor=(int*)w;     w += (size_t)CTOT * 4;
    int*    bsum = (int*)w;     w += 2048 * 4;
    __bf16* XbT  = (__bf16*)w;  w += (size_t)XTTOT * 4096 * 16; // 61.54 MB (new path only)
    size_t required_new = (size_t)(w - (char*)d_ws);
    int* cnt0 = segc, *cnt1 = segc + 8, *cnt2 = segc + 16;
    const bool use_glds = (ws_size >= required_new);

    // ---- source table: order adj0, inc1 | inc1t, adjd1, adju1, inc2 | inc2t, adjd2
    const int bases[8] = {15, 3, 9, 21, 18, 6, 12, 24};
    const int kbase[8] = {KB_L0, KB_L0, KB_L1, KB_L1, KB_L1, KB_L1, KB_L2, KB_L2};
    const int mulS [8] = {2, 2, 3, 3, 3, 3, 2, 2};
    const int slot [8] = {0, 1, 0, 1, 1, 2, 0, 1};
    const int tbase[8] = {0, 20000, 0, 20000, 20000, 80000, 0, 60000};
    SrcTab st;
    int run = 0;
    for (int s = 0; s < 8; ++s) {
        st.rows[s] = (const int*)d_in[bases[s]];
        st.cols[s] = (const int*)d_in[bases[s] + 1];
        st.vals[s] = (const float*)d_in[bases[s] + 2];
        st.kbase[s] = kbase[s]; st.mulS[s] = mulS[s];
        st.slot[s] = slot[s];   st.tbase[s] = tbase[s];
        st.pre[s] = run;
        run += in_sizes[bases[s]];
    }
    st.pre[8] = run;
    const int total = run;

    WTab wt;
    for (int i = 0; i < 7; ++i) wt.w[i] = (const float*)d_in[30 + i];

    // ---- CSR build + weight/X convert + seg counts ----
    zero_kernel<<<512, 256, 0, stream>>>((float4*)cnt, (CTOT * 4 + 3 * BB * CC * 4 + 128) / 16);
    hist_all<<<(total + 255) / 256, 256, 0, stream>>>(st, cnt, total);
    if (use_glds) {
        convert_w_tiled<<<224, 256, 0, stream>>>(wt, Wt);
        XcvtTab xt;
        xt.src[0] = x0; xt.src[1] = x1; xt.src[2] = x2;
        xt.tstart[0] = XT0; xt.tstart[1] = XT1; xt.tstart[2] = XT2; xt.tstart[3] = XTTOT;
        xt.nrows[0] = NN0; xt.nrows[1] = NN1; xt.nrows[2] = NN2;
        convert_x_tiled<<<XTTOT, 256, 0, stream>>>(xt, XbT);
    } else {
        convert_w_old<<<7 * 256, 256, 0, stream>>>(wt, Wt);
    }
    seg_count_all<<<(NN1 + 255) / 256, 256, 0, stream>>>(belong0, belong1, belong2, segc);
    scan_blocks<<<NBLK, 256, 0, stream>>>(cnt, CTOT, rstart, bsum);
    scan_bsum<<<1, 256, 0, stream>>>(bsum, NBLK);
    scan_add<<<NBLK, 256, 0, stream>>>(rstart, bsum, CTOT, cursor);
    {
        int half = (total + 1) / 2;
        scatter_all<<<(half + 255) / 256, 256, 0, stream>>>(st, cursor, epair, total, half);
    }

    auto launch_gemm = [&](GemmTab& g, int njobs) {
        dim3 grid((NN1 + 127) / 128, 2, njobs);
        if (use_glds) gemm_glds<<<grid, 256, 0, stream>>>(g, Wt, XbT, T);
        else          gemm_level<<<grid, 256, 0, stream>>>(g, Wt, T);
    };

    // ---- level 0: T = [x0@W00 (20k) | x1@W10 (60k)] ----
    {
        GemmTab g;
        g.j[0] = {x0, XT0, 0, 0, NN0};
        g.j[1] = {x1, XT1, 1, 20000, NN1};
        launch_gemm(g, 2);
        spmm_level<<<(NN0 + 3) / 4, 256, 0, stream>>>(epair, rstart, T, accb, KB_L0, 2, NN0);
        pool_sigmoid<<<(NN0 + 63) / 64, 256, 0, stream>>>(accb, belong0, poolh, NN0);
    }
    // ---- level 1: T = [x0@W01 (20k) | x1@W11 (60k) | x2@W21 (40k)] ----
    {
        GemmTab g;
        g.j[0] = {x0, XT0, 2, 0, NN0};
        g.j[1] = {x1, XT1, 3, 20000, NN1};
        g.j[2] = {x2, XT2, 4, 80000, NN2};
        launch_gemm(g, 3);
        spmm_level<<<(NN1 + 3) / 4, 256, 0, stream>>>(epair, rstart, T, accb, KB_L1, 3, NN1);
        pool_sigmoid<<<(NN1 + 63) / 64, 256, 0, stream>>>(accb, belong1, poolh + BB * CC, NN1);
    }
    // ---- level 2: T = [x1@W12 (60k) | x2@W22 (40k)] ----
    {
        GemmTab g;
        g.j[0] = {x1, XT1, 5, 0, NN1};
        g.j[1] = {x2, XT2, 6, 60000, NN2};
        launch_gemm(g, 2);
        spmm_level<<<(NN2 + 3) / 4, 256, 0, stream>>>(epair, rstart, T, accb, KB_L2, 2, NN2);
        pool_sigmoid<<<(NN2 + 63) / 64, 256, 0, stream>>>(accb, belong2, poolh + 2 * BB * CC, NN2);
    }

    // ---- combine ----
    final_head<<<BB, 64, 0, stream>>>(poolh, poolh + BB * CC, poolh + 2 * BB * CC,
                                      cnt0, cnt1, cnt2,
                                      (const float*)d_in[37], (const float*)d_in[38],
                                      (const float*)d_in[39], (const float*)d_in[40],
                                      (const float*)d_in[41], (const float*)d_in[42],
                                      (float*)d_out);
}